// Round 8
// baseline (359.604 us; speedup 1.0000x reference)
//
#include <hip/hip_runtime.h>
#include <hip/hip_cooperative_groups.h>

namespace cg = cooperative_groups;

#define NN 50000
#define DD 128
#define SLOPE 0.01f
#define NB 782        // buckets of 64 nodes: bucket = v>>6
#define BCAP 2560     // per-bucket cap; mean 2046, sigma 45 -> +11 sigma
#define ECH 2048      // edges per mega block (782*2048 >= 1.6M), 8/thread
#define EPT 8
#define OVCAP 8192
#define HP 136        // Hs row pitch (bf16)
// convert_bin (fallback) params
#define FECH 6144
#define BST 512
#define PB2 2

using bf16x8 = __attribute__((ext_vector_type(8))) short;
using f32x4  = __attribute__((ext_vector_type(4))) float;

// ---------------- bf16 helpers (RNE) ----------------
__device__ inline float bflo(unsigned int w) { return __uint_as_float(w << 16); }
__device__ inline float bfhi(unsigned int w) { return __uint_as_float(w & 0xffff0000u); }
__device__ inline float sbf(short s) {
    return __uint_as_float(((unsigned int)(unsigned short)s) << 16);
}
__device__ inline unsigned int rnebf(float f) {
    unsigned int u = __float_as_uint(f);
    return (u + 0x7fffu + ((u >> 16) & 1u)) >> 16;
}
__device__ inline unsigned int pack2(float lo, float hi) {
    return rnebf(lo) | (rnebf(hi) << 16);
}
__device__ inline uint4 pack8f(const float* f) {
    uint4 o;
    o.x = pack2(f[0], f[1]); o.y = pack2(f[2], f[3]);
    o.z = pack2(f[4], f[5]); o.w = pack2(f[6], f[7]);
    return o;
}
__device__ inline void addrow(float* acc, uint4 r) {
    acc[0] += bflo(r.x); acc[1] += bfhi(r.x);
    acc[2] += bflo(r.y); acc[3] += bfhi(r.y);
    acc[4] += bflo(r.z); acc[5] += bfhi(r.z);
    acc[6] += bflo(r.w); acc[7] += bfhi(r.w);
}

struct P1 {
    unsigned int srt[ECH];   // 8 KB
    int off[NB];             // 3.1 KB
    int pos[NB];             // 3.1 KB
    int wsum[4];
};
struct P2 {
    unsigned short sorted[BCAP];   // 5 KB
    unsigned short Hs[64][HP];     // 17 KB
    int cnt[64]; int off2[65]; int pos2[64];
};

// ===========================================================================
// Single cooperative kernel: init -> bin+convert -> grid.sync -> gather+GEMM
// ===========================================================================
__global__ __launch_bounds__(256, 4) void mega(
    const float* __restrict__ E, const float* __restrict__ W1,
    const float* __restrict__ W2,
    const float* __restrict__ b1, const float* __restrict__ b2,
    const int* __restrict__ src, const int* __restrict__ dst, int n_edges,
    unsigned short* __restrict__ Ebf, unsigned short* __restrict__ W1b,
    unsigned short* __restrict__ W2b,
    int* __restrict__ gtail, unsigned int* __restrict__ stag,
    int* __restrict__ ovf_cnt, int2* __restrict__ ovf,
    float* __restrict__ out)
{
    __shared__ union ShU { P1 p1; P2 p2; } sh;
    __shared__ int s_novf;

    cg::grid_group grid = cg::this_grid();
    const int tid = threadIdx.x;
    const int bid = blockIdx.x;
    const int gid = bid * 256 + tid;
    const int gsz = gridDim.x * 256;

    // ---------------- phase 0: zero gtail + ovf_cnt ----------------
    for (int i = gid; i < NB; i += gsz) gtail[i] = 0;
    if (gid == 0) *ovf_cnt = 0;
    grid.sync();

    // ---------------- phase 1a: bin my 2048-edge chunk ----------------
    {
        const int e0 = bid * ECH;
        const int m = min(ECH, n_edges - e0);
        int uu[EPT], vv[EPT];
        #pragma unroll
        for (int k = 0; k < EPT; ++k) {
            int i = tid + 256 * k;
            if (i < m) { uu[k] = src[e0 + i]; vv[k] = dst[e0 + i]; }
            else vv[k] = -1;
        }
        for (int b = tid; b < NB; b += 256) sh.p1.pos[b] = 0;
        __syncthreads();
        #pragma unroll
        for (int k = 0; k < EPT; ++k)
            if (vv[k] >= 0) atomicAdd(&sh.p1.pos[vv[k] >> 6], 1);
        __syncthreads();

        // exclusive scan of pos -> off (thread t covers buckets [4t,4t+4))
        const int lane = tid & 63, w = tid >> 6;
        int b0 = tid * 4;
        int loc[4]; int s = 0;
        #pragma unroll
        for (int j = 0; j < 4; ++j) {
            int bb = b0 + j;
            int cv = (bb < NB) ? sh.p1.pos[bb] : 0;
            loc[j] = s; s += cv;
        }
        int incl = s;
        #pragma unroll
        for (int d = 1; d < 64; d <<= 1) {
            int t2 = __shfl_up(incl, d);
            if (lane >= d) incl += t2;
        }
        if (lane == 63) sh.p1.wsum[w] = incl;
        __syncthreads();
        int wbase = 0;
        for (int w2 = 0; w2 < w; ++w2) wbase += sh.p1.wsum[w2];
        int base = wbase + incl - s;
        #pragma unroll
        for (int j = 0; j < 4; ++j) {
            int bb = b0 + j;
            if (bb < NB) { sh.p1.off[bb] = base + loc[j]; sh.p1.pos[bb] = base + loc[j]; }
        }
        __syncthreads();

        #pragma unroll
        for (int k = 0; k < EPT; ++k) {
            if (vv[k] >= 0) {
                int p = atomicAdd(&sh.p1.pos[vv[k] >> 6], 1);
                sh.p1.srt[p] = (unsigned int)uu[k]
                             | ((unsigned int)(vv[k] & 63) << 16);
            }
        }
        __syncthreads();

        // flush: one global atomic per nonempty bucket, contiguous run copy
        for (int bb = tid; bb < NB; bb += 256) {
            int s0 = sh.p1.off[bb], e1 = sh.p1.pos[bb];
            int c = e1 - s0;
            if (!c) continue;
            int g = atomicAdd(&gtail[bb], c);
            unsigned int* dstp = stag + (size_t)bb * BCAP;
            for (int k = 0; k < c; ++k) {
                int gp = g + k;
                unsigned int r = sh.p1.srt[s0 + k];
                if (gp < BCAP) {
                    dstp[gp] = r;
                } else {
                    int oi = atomicAdd(ovf_cnt, 1);
                    if (oi < OVCAP)
                        ovf[oi] = make_int2((int)(r & 0xffffu),
                                            bb * 64 + (int)((r >> 16) & 63));
                }
            }
        }
    }

    // ---------------- phase 1b: convert E/W1/W2 fp32 -> bf16 ----------------
    {
        const int NE8 = NN * DD / 8;          // 800000
        const int NW8 = DD * DD / 8;          // 2048
        const int NCV = NE8 + 2 * NW8;
        for (int t = gid; t < NCV; t += gsz) {
            const float* s2; unsigned short* d2; int idx;
            if (t < NE8)            { s2 = E;  d2 = Ebf; idx = t; }
            else if (t < NE8 + NW8) { s2 = W1; d2 = W1b; idx = t - NE8; }
            else                    { s2 = W2; d2 = W2b; idx = t - NE8 - NW8; }
            float4 a = ((const float4*)s2)[(size_t)idx * 2];
            float4 b = ((const float4*)s2)[(size_t)idx * 2 + 1];
            uint4 o;
            o.x = pack2(a.x, a.y); o.y = pack2(a.z, a.w);
            o.z = pack2(b.x, b.y); o.w = pack2(b.z, b.w);
            ((uint4*)d2)[idx] = o;
        }
    }

    grid.sync();

    // ---------------- phase 2: gather + GEMM, block = bucket ----------------
    const int b = bid;
    int len = gtail[b]; len = len < BCAP ? len : BCAP;
    const unsigned int* seg = stag + (size_t)b * BCAP;

    if (tid == 0) { int t = *ovf_cnt; s_novf = t < OVCAP ? t : OVCAP; }
    if (tid < 64) sh.p2.cnt[tid] = 0;
    __syncthreads();
    for (int i = tid; i < len; i += 256)
        atomicAdd(&sh.p2.cnt[(seg[i] >> 16) & 63], 1);
    __syncthreads();
    if (tid == 0) {
        int a = 0;
        for (int j = 0; j < 64; ++j) {
            sh.p2.off2[j] = a; sh.p2.pos2[j] = a; a += sh.p2.cnt[j];
        }
        sh.p2.off2[64] = a;
    }
    __syncthreads();
    for (int i = tid; i < len; i += 256) {
        unsigned int r = seg[i];
        int p = atomicAdd(&sh.p2.pos2[(r >> 16) & 63], 1);
        sh.p2.sorted[p] = (unsigned short)(r & 0xffffu);
    }
    __syncthreads();
    const int novf = s_novf;

    // gather: 16 lanes per node x 16 nodes per pass, 4 passes
    {
        const int g = tid >> 4;
        const int c = tid & 15;
        const uint4* E4 = (const uint4*)Ebf;
        for (int p4 = 0; p4 < 4; ++p4) {
            int nl = p4 * 16 + g;
            int v = b * 64 + nl;
            if (v >= NN) continue;
            float acc[8] = {};
            int i = sh.p2.off2[nl], e1 = sh.p2.off2[nl + 1];
            for (; i + 8 <= e1; i += 8) {
                uint4 r0 = E4[(size_t)sh.p2.sorted[i]     * 16 + c];
                uint4 r1 = E4[(size_t)sh.p2.sorted[i + 1] * 16 + c];
                uint4 r2 = E4[(size_t)sh.p2.sorted[i + 2] * 16 + c];
                uint4 r3 = E4[(size_t)sh.p2.sorted[i + 3] * 16 + c];
                uint4 r4 = E4[(size_t)sh.p2.sorted[i + 4] * 16 + c];
                uint4 r5 = E4[(size_t)sh.p2.sorted[i + 5] * 16 + c];
                uint4 r6 = E4[(size_t)sh.p2.sorted[i + 6] * 16 + c];
                uint4 r7 = E4[(size_t)sh.p2.sorted[i + 7] * 16 + c];
                addrow(acc, r0); addrow(acc, r1); addrow(acc, r2); addrow(acc, r3);
                addrow(acc, r4); addrow(acc, r5); addrow(acc, r6); addrow(acc, r7);
            }
            for (; i + 2 <= e1; i += 2) {
                uint4 r0 = E4[(size_t)sh.p2.sorted[i]     * 16 + c];
                uint4 r1 = E4[(size_t)sh.p2.sorted[i + 1] * 16 + c];
                addrow(acc, r0); addrow(acc, r1);
            }
            if (i < e1) addrow(acc, E4[(size_t)sh.p2.sorted[i] * 16 + c]);

            if (novf > 0) {
                for (int k = 0; k < novf; ++k) {
                    int2 e = ovf[k];
                    if (e.y == v) addrow(acc, E4[(size_t)e.x * 16 + c]);
                }
            }
            *(uint4*)&sh.p2.Hs[nl][c * 8] = pack8f(acc);
        }
    }
    __syncthreads();

    // GEMM: wave w -> node rows w*16 .. w*16+15
    const int wave = tid >> 6;
    const int lane = tid & 63;
    const int v0 = b * 64 + wave * 16;
    if (v0 >= NN) return;
    const int m = lane & 15;
    const int quad = lane >> 4;

    bf16x8 aH[4], aE[4];
    const unsigned short* hrow = &sh.p2.Hs[wave * 16 + m][quad * 8];
    const unsigned short* erow = Ebf + (size_t)(v0 + m) * DD + quad * 8;
    #pragma unroll
    for (int ks = 0; ks < 4; ++ks) {
        bf16x8 h8 = *(const bf16x8*)(hrow + ks * 32);
        bf16x8 e8 = *(const bf16x8*)(erow + ks * 32);
        aH[ks] = h8;
        bf16x8 eh;
        #pragma unroll
        for (int j = 0; j < 8; ++j)
            eh[j] = (short)rnebf(sbf(h8[j]) * sbf(e8[j]));
        aE[ks] = eh;
    }

    #pragma unroll
    for (int jt = 0; jt < 8; ++jt) {
        const int j0 = jt * 16;
        const unsigned short* w1r = W1b + (size_t)(j0 + m) * DD + quad * 8;
        const unsigned short* w2r = W2b + (size_t)(j0 + m) * DD + quad * 8;
        f32x4 acc1 = {0.f, 0.f, 0.f, 0.f}, acc2 = {0.f, 0.f, 0.f, 0.f};
        #pragma unroll
        for (int ks = 0; ks < 4; ++ks) {
            bf16x8 bw1 = *(const bf16x8*)(w1r + ks * 32);
            bf16x8 bw2 = *(const bf16x8*)(w2r + ks * 32);
            acc1 = __builtin_amdgcn_mfma_f32_16x16x32_bf16(aH[ks], bw1, acc1, 0, 0, 0);
            acc2 = __builtin_amdgcn_mfma_f32_16x16x32_bf16(aE[ks], bw2, acc2, 0, 0, 0);
        }
        const float bb1 = b1[j0 + m], bb2 = b2[j0 + m];
        #pragma unroll
        for (int i = 0; i < 4; ++i) {
            int row = v0 + quad * 4 + i;
            if (row < NN) {
                float x1 = acc1[i] + bb1; x1 = x1 > 0.f ? x1 : SLOPE * x1;
                float x2 = acc2[i] + bb2; x2 = x2 > 0.f ? x2 : SLOPE * x2;
                out[(size_t)row * DD + j0 + m] = x1 + x2;
            }
        }
    }
}

// ===================== fallback: round-7 3-dispatch path ====================
__global__ __launch_bounds__(BST) void convert_bin(
    const float* __restrict__ E, const float* __restrict__ W1,
    const float* __restrict__ W2, const int* __restrict__ src,
    const int* __restrict__ dst, unsigned short* __restrict__ Ebf,
    unsigned short* __restrict__ W1b, unsigned short* __restrict__ W2b,
    int* __restrict__ gtail, unsigned int* __restrict__ stag,
    int* __restrict__ ovf_cnt, int2* __restrict__ ovf,
    int n_edges, int nbin)
{
    const int tid = threadIdx.x;
    if (blockIdx.x >= nbin) {
        const int NE8 = NN * DD / 8;
        const int NW8 = DD * DD / 8;
        int t = (blockIdx.x - nbin) * BST + tid;
        const float* s; unsigned short* d; int idx;
        if (t < NE8)                { s = E;  d = Ebf; idx = t; }
        else if (t < NE8 + NW8)     { s = W1; d = W1b; idx = t - NE8; }
        else if (t < NE8 + 2 * NW8) { s = W2; d = W2b; idx = t - NE8 - NW8; }
        else return;
        float4 a = ((const float4*)s)[(size_t)idx * 2];
        float4 b = ((const float4*)s)[(size_t)idx * 2 + 1];
        uint4 o;
        o.x = pack2(a.x, a.y); o.y = pack2(a.z, a.w);
        o.z = pack2(b.x, b.y); o.w = pack2(b.z, b.w);
        ((uint4*)d)[idx] = o;
        return;
    }
    __shared__ unsigned int srt[FECH];
    __shared__ int cnt[NB], off[NB], pos[NB];
    __shared__ int wsum[BST / 64];
    const int e0 = blockIdx.x * FECH;
    const int m = min(FECH, n_edges - e0);
    for (int b = tid; b < NB; b += BST) cnt[b] = 0;
    __syncthreads();
    for (int i = tid; i < m; i += BST)
        atomicAdd(&cnt[dst[e0 + i] >> 6], 1);
    __syncthreads();
    const int lane = tid & 63, w = tid >> 6;
    int b0 = tid * PB2;
    int loc[PB2]; int s = 0;
    #pragma unroll
    for (int j = 0; j < PB2; ++j) {
        int bb = b0 + j;
        int cv = (bb < NB) ? cnt[bb] : 0;
        loc[j] = s; s += cv;
    }
    int incl = s;
    #pragma unroll
    for (int d = 1; d < 64; d <<= 1) {
        int t2 = __shfl_up(incl, d);
        if (lane >= d) incl += t2;
    }
    if (lane == 63) wsum[w] = incl;
    __syncthreads();
    int wbase = 0;
    for (int w2 = 0; w2 < w; ++w2) wbase += wsum[w2];
    int base = wbase + incl - s;
    #pragma unroll
    for (int j = 0; j < PB2; ++j) {
        int bb = b0 + j;
        if (bb < NB) { off[bb] = base + loc[j]; pos[bb] = base + loc[j]; }
    }
    __syncthreads();
    for (int i = tid; i < m; i += BST) {
        int v = dst[e0 + i];
        int u = src[e0 + i];
        int p = atomicAdd(&pos[v >> 6], 1);
        srt[p] = (unsigned int)u | ((unsigned int)(v & 63) << 16);
    }
    __syncthreads();
    for (int bb = tid; bb < NB; bb += BST) {
        int c = cnt[bb];
        if (!c) continue;
        int g = atomicAdd(&gtail[bb], c);
        int s0 = off[bb];
        unsigned int* dstp = stag + (size_t)bb * BCAP;
        for (int k = 0; k < c; ++k) {
            int gp = g + k;
            unsigned int r = srt[s0 + k];
            if (gp < BCAP) dstp[gp] = r;
            else {
                int oi = atomicAdd(ovf_cnt, 1);
                if (oi < OVCAP)
                    ovf[oi] = make_int2((int)(r & 0xffffu),
                                        bb * 64 + (int)((r >> 16) & 63));
            }
        }
    }
}

__global__ __launch_bounds__(256) void bucket_fused(
    const unsigned short* __restrict__ Ebf, const int* __restrict__ gtail,
    const unsigned int* __restrict__ stag, const int* __restrict__ ovf_cnt,
    const int2* __restrict__ ovf,
    const unsigned short* __restrict__ W1b, const unsigned short* __restrict__ W2b,
    const float* __restrict__ b1, const float* __restrict__ b2,
    float* __restrict__ out)
{
    __shared__ unsigned short sorted[BCAP];
    __shared__ unsigned short Hs[64][HP];
    __shared__ int cnt[64], off[65], pos[64];
    __shared__ int s_novf;
    const int b = blockIdx.x;
    const int tid = threadIdx.x;
    int len = gtail[b]; len = len < BCAP ? len : BCAP;
    const unsigned int* seg = stag + (size_t)b * BCAP;
    if (tid == 0) { int t = *ovf_cnt; s_novf = t < OVCAP ? t : OVCAP; }
    if (tid < 64) cnt[tid] = 0;
    __syncthreads();
    for (int i = tid; i < len; i += 256)
        atomicAdd(&cnt[(seg[i] >> 16) & 63], 1);
    __syncthreads();
    if (tid == 0) {
        int a = 0;
        for (int j = 0; j < 64; ++j) { off[j] = a; pos[j] = a; a += cnt[j]; }
        off[64] = a;
    }
    __syncthreads();
    for (int i = tid; i < len; i += 256) {
        unsigned int r = seg[i];
        int p = atomicAdd(&pos[(r >> 16) & 63], 1);
        sorted[p] = (unsigned short)(r & 0xffffu);
    }
    __syncthreads();
    const int novf = s_novf;
    const int g = tid >> 4;
    const int c = tid & 15;
    const uint4* E4 = (const uint4*)Ebf;
    for (int p4 = 0; p4 < 4; ++p4) {
        int nl = p4 * 16 + g;
        int v = b * 64 + nl;
        if (v >= NN) continue;
        float acc[8] = {};
        int i = off[nl], e1 = off[nl + 1];
        for (; i + 8 <= e1; i += 8) {
            uint4 r0 = E4[(size_t)sorted[i]     * 16 + c];
            uint4 r1 = E4[(size_t)sorted[i + 1] * 16 + c];
            uint4 r2 = E4[(size_t)sorted[i + 2] * 16 + c];
            uint4 r3 = E4[(size_t)sorted[i + 3] * 16 + c];
            uint4 r4 = E4[(size_t)sorted[i + 4] * 16 + c];
            uint4 r5 = E4[(size_t)sorted[i + 5] * 16 + c];
            uint4 r6 = E4[(size_t)sorted[i + 6] * 16 + c];
            uint4 r7 = E4[(size_t)sorted[i + 7] * 16 + c];
            addrow(acc, r0); addrow(acc, r1); addrow(acc, r2); addrow(acc, r3);
            addrow(acc, r4); addrow(acc, r5); addrow(acc, r6); addrow(acc, r7);
        }
        for (; i + 2 <= e1; i += 2) {
            uint4 r0 = E4[(size_t)sorted[i]     * 16 + c];
            uint4 r1 = E4[(size_t)sorted[i + 1] * 16 + c];
            addrow(acc, r0); addrow(acc, r1);
        }
        if (i < e1) addrow(acc, E4[(size_t)sorted[i] * 16 + c]);
        if (novf > 0) {
            for (int k = 0; k < novf; ++k) {
                int2 e = ovf[k];
                if (e.y == v) addrow(acc, E4[(size_t)e.x * 16 + c]);
            }
        }
        *(uint4*)&Hs[nl][c * 8] = pack8f(acc);
    }
    __syncthreads();
    const int wave = tid >> 6;
    const int lane = tid & 63;
    const int v0 = b * 64 + wave * 16;
    if (v0 >= NN) return;
    const int m = lane & 15;
    const int quad = lane >> 4;
    bf16x8 aH[4], aE[4];
    const unsigned short* hrow = &Hs[wave * 16 + m][quad * 8];
    const unsigned short* erow = Ebf + (size_t)(v0 + m) * DD + quad * 8;
    #pragma unroll
    for (int ks = 0; ks < 4; ++ks) {
        bf16x8 h8 = *(const bf16x8*)(hrow + ks * 32);
        bf16x8 e8 = *(const bf16x8*)(erow + ks * 32);
        aH[ks] = h8;
        bf16x8 eh;
        #pragma unroll
        for (int j = 0; j < 8; ++j)
            eh[j] = (short)rnebf(sbf(h8[j]) * sbf(e8[j]));
        aE[ks] = eh;
    }
    #pragma unroll
    for (int jt = 0; jt < 8; ++jt) {
        const int j0 = jt * 16;
        const unsigned short* w1r = W1b + (size_t)(j0 + m) * DD + quad * 8;
        const unsigned short* w2r = W2b + (size_t)(j0 + m) * DD + quad * 8;
        f32x4 acc1 = {0.f, 0.f, 0.f, 0.f}, acc2 = {0.f, 0.f, 0.f, 0.f};
        #pragma unroll
        for (int ks = 0; ks < 4; ++ks) {
            bf16x8 bw1 = *(const bf16x8*)(w1r + ks * 32);
            bf16x8 bw2 = *(const bf16x8*)(w2r + ks * 32);
            acc1 = __builtin_amdgcn_mfma_f32_16x16x32_bf16(aH[ks], bw1, acc1, 0, 0, 0);
            acc2 = __builtin_amdgcn_mfma_f32_16x16x32_bf16(aE[ks], bw2, acc2, 0, 0, 0);
        }
        const float bb1 = b1[j0 + m], bb2 = b2[j0 + m];
        #pragma unroll
        for (int i = 0; i < 4; ++i) {
            int row = v0 + quad * 4 + i;
            if (row < NN) {
                float x1 = acc1[i] + bb1; x1 = x1 > 0.f ? x1 : SLOPE * x1;
                float x2 = acc2[i] + bb2; x2 = x2 > 0.f ? x2 : SLOPE * x2;
                out[(size_t)row * DD + j0 + m] = x1 + x2;
            }
        }
    }
}

// ============== minimal fallback (ws too small): fp32 atomics ==============
__global__ __launch_bounds__(256) void scatter_add(
    const float* __restrict__ E, const int* __restrict__ src,
    const int* __restrict__ dst, float* __restrict__ H, int n_edges)
{
    int t = blockIdx.x * 256 + threadIdx.x;
    int e = t >> 5;
    if (e >= n_edges) return;
    int c = t & 31;
    float4 a = ((const float4*)E)[(size_t)src[e] * 32 + c];
    float* hp = H + (size_t)dst[e] * DD + c * 4;
    atomicAdd(hp + 0, a.x); atomicAdd(hp + 1, a.y);
    atomicAdd(hp + 2, a.z); atomicAdd(hp + 3, a.w);
}

__global__ __launch_bounds__(256) void fused_mlp(
    const float* __restrict__ E, const float* __restrict__ H,
    const float* __restrict__ W1, const float* __restrict__ b1,
    const float* __restrict__ W2, const float* __restrict__ b2,
    float* __restrict__ out)
{
    __shared__ float Hsf[32][DD];
    __shared__ float EHs[32][DD];
    __shared__ float W1s[DD][20];
    __shared__ float W2s[DD][20];
    const int tid = threadIdx.x;
    const int v0 = blockIdx.x * 32;
    const int nvalid = min(32, NN - v0);
    for (int i = 0; i < 4; ++i) {
        int f = tid + 256 * i;
        int n = f >> 5, c = f & 31;
        float4 h = make_float4(0.f, 0.f, 0.f, 0.f);
        float4 eh = h;
        if (n < nvalid) {
            h = ((const float4*)H)[(size_t)(v0 + n) * 32 + c];
            float4 e4 = ((const float4*)E)[(size_t)(v0 + n) * 32 + c];
            eh = make_float4(e4.x * h.x, e4.y * h.y, e4.z * h.z, e4.w * h.w);
        }
        *((float4*)&Hsf[n][c * 4]) = h;
        *((float4*)&EHs[n][c * 4]) = eh;
    }
    const int jg = tid & 63;
    const int n0 = (tid >> 6) * 8;
    float acc1a[8] = {}, acc1b[8] = {}, acc2a[8] = {}, acc2b[8] = {};
    for (int t8 = 0; t8 < 8; ++t8) {
        const int k0 = t8 * 16;
        __syncthreads();
        for (int i = 0; i < 8; ++i) {
            int f = tid + 256 * i;
            int j = f >> 4, kk = f & 15;
            W1s[j][kk] = W1[j * DD + k0 + kk];
            W2s[j][kk] = W2[j * DD + k0 + kk];
        }
        __syncthreads();
        for (int c = 0; c < 4; ++c) {
            float4 w1a = *((const float4*)&W1s[jg][c * 4]);
            float4 w1b = *((const float4*)&W1s[jg + 64][c * 4]);
            float4 w2a = *((const float4*)&W2s[jg][c * 4]);
            float4 w2b = *((const float4*)&W2s[jg + 64][c * 4]);
            const int kk = k0 + c * 4;
            for (int n = 0; n < 8; ++n) {
                float4 h = *((const float4*)&Hsf[n0 + n][kk]);
                float4 eh = *((const float4*)&EHs[n0 + n][kk]);
                acc1a[n] += h.x * w1a.x + h.y * w1a.y + h.z * w1a.z + h.w * w1a.w;
                acc1b[n] += h.x * w1b.x + h.y * w1b.y + h.z * w1b.z + h.w * w1b.w;
                acc2a[n] += eh.x * w2a.x + eh.y * w2a.y + eh.z * w2a.z + eh.w * w2a.w;
                acc2b[n] += eh.x * w2b.x + eh.y * w2b.y + eh.z * w2b.z + eh.w * w2b.w;
            }
        }
    }
    const float b1a = b1[jg], b1b = b1[jg + 64];
    const float b2a = b2[jg], b2b = b2[jg + 64];
    for (int n = 0; n < 8; ++n) {
        if (n0 + n < nvalid) {
            const int v = v0 + n0 + n;
            float x1 = acc1a[n] + b1a; x1 = x1 > 0.f ? x1 : SLOPE * x1;
            float x2 = acc2a[n] + b2a; x2 = x2 > 0.f ? x2 : SLOPE * x2;
            out[(size_t)v * DD + jg] = x1 + x2;
            float y1 = acc1b[n] + b1b; y1 = y1 > 0.f ? y1 : SLOPE * y1;
            float y2 = acc2b[n] + b2b; y2 = y2 > 0.f ? y2 : SLOPE * y2;
            out[(size_t)v * DD + jg + 64] = y1 + y2;
        }
    }
}
// ===========================================================================

extern "C" void kernel_launch(void* const* d_in, const int* in_sizes, int n_in,
                              void* d_out, int out_size, void* d_ws, size_t ws_size,
                              hipStream_t stream)
{
    const float* E  = (const float*)d_in[0];
    const float* W1 = (const float*)d_in[1];
    const float* b1 = (const float*)d_in[2];
    const float* W2 = (const float*)d_in[3];
    const float* b2 = (const float*)d_in[4];
    const int* src  = (const int*)d_in[5];
    const int* dst  = (const int*)d_in[6];
    float* out = (float*)d_out;
    int n_edges = in_sizes[5];

    char* ws = (char*)d_ws;
    auto al = [](size_t x) { return (x + 255) & ~(size_t)255; };

    const size_t off_tail = 0;
    const size_t off_ovfc = (size_t)NB * 4;
    const size_t off_ovf  = al(off_ovfc + 4);
    const size_t off_stag = al(off_ovf + (size_t)OVCAP * 8);
    const size_t off_Ebf  = al(off_stag + (size_t)NB * BCAP * 4);
    const size_t off_W1b  = al(off_Ebf + (size_t)NN * DD * 2);
    const size_t off_W2b  = al(off_W1b + (size_t)DD * DD * 2);
    const size_t need_bf  = off_W2b + (size_t)DD * DD * 2;      // ~21 MB

    if (ws_size >= need_bf) {
        int*  gtail   = (int*)(ws + off_tail);
        int*  ovf_cnt = (int*)(ws + off_ovfc);
        int2* ovf     = (int2*)(ws + off_ovf);
        unsigned int*   stag = (unsigned int*)(ws + off_stag);
        unsigned short* Ebf  = (unsigned short*)(ws + off_Ebf);
        unsigned short* W1b  = (unsigned short*)(ws + off_W1b);
        unsigned short* W2b  = (unsigned short*)(ws + off_W2b);

        // --- preferred: single cooperative kernel ---
        int dev = 0, coop = 0;
        hipGetDevice(&dev);
        hipDeviceGetAttribute(&coop, hipDeviceAttributeCooperativeLaunch, dev);
        if (coop) {
            void* args[] = {
                (void*)&E, (void*)&W1, (void*)&W2, (void*)&b1, (void*)&b2,
                (void*)&src, (void*)&dst, (void*)&n_edges,
                (void*)&Ebf, (void*)&W1b, (void*)&W2b,
                (void*)&gtail, (void*)&stag, (void*)&ovf_cnt, (void*)&ovf,
                (void*)&out
            };
            hipError_t err = hipLaunchCooperativeKernel(
                (const void*)mega, dim3(NB), dim3(256), args, 0, stream);
            if (err == hipSuccess) return;
        }

        // --- fallback: round-7 3-dispatch path ---
        const int nbin = (n_edges + FECH - 1) / FECH;
        const int ncv  = NN * DD / 8 + 2 * (DD * DD / 8);
        const int ncvb = (ncv + BST - 1) / BST;
        hipMemsetAsync(ws, 0, off_ovf, stream);
        convert_bin<<<nbin + ncvb, BST, 0, stream>>>(
            E, W1, W2, src, dst, Ebf, W1b, W2b,
            gtail, stag, ovf_cnt, ovf, n_edges, nbin);
        bucket_fused<<<NB, 256, 0, stream>>>(
            Ebf, gtail, stag, ovf_cnt, ovf, W1b, W2b, b1, b2, out);
        return;
    }

    // fallback: fp32 atomics into H (= ws if it fits, else out), then fused MLP
    const size_t hbytes = (size_t)NN * DD * sizeof(float);
    float* H = (ws_size >= hbytes) ? (float*)ws : out;
    hipMemsetAsync(H, 0, hbytes, stream);
    scatter_add<<<((n_edges * 32) + 255) / 256, 256, 0, stream>>>(
        E, src, dst, H, n_edges);
    fused_mlp<<<(NN + 31) / 32, 256, 0, stream>>>(E, H, W1, b1, W2, b2, out);
}

// Round 9
// 323.405 us; speedup vs baseline: 1.1119x; 1.1119x over previous
//
#include <hip/hip_runtime.h>
#include <hip/hip_cooperative_groups.h>

namespace cg = cooperative_groups;

#define NN 50000
#define DD 128
#define SLOPE 0.01f
#define NB 782        // buckets of 64 nodes: bucket = v>>6; also grid size
#define NBLK NB       // chunks == blocks
#define ECH 2048      // edges per mega block (782*2048 >= 1.6M)
#define EPT 8
#define SLICE 16      // ints per (bucket,chunk) cell = one 64B line
#define RAWCAP 2560
#define OVCAP 8192
#define HP 136        // Hs row pitch (bf16)
// fallback (round-7) params
#define FECH 6144
#define BST 512
#define PB2 2
#define BCAP 2560

using bf16x8 = __attribute__((ext_vector_type(8))) short;
using f32x4  = __attribute__((ext_vector_type(4))) float;

// ---------------- bf16 helpers (RNE) ----------------
__device__ inline float bflo(unsigned int w) { return __uint_as_float(w << 16); }
__device__ inline float bfhi(unsigned int w) { return __uint_as_float(w & 0xffff0000u); }
__device__ inline float sbf(short s) {
    return __uint_as_float(((unsigned int)(unsigned short)s) << 16);
}
__device__ inline unsigned int rnebf(float f) {
    unsigned int u = __float_as_uint(f);
    return (u + 0x7fffu + ((u >> 16) & 1u)) >> 16;
}
__device__ inline unsigned int pack2(float lo, float hi) {
    return rnebf(lo) | (rnebf(hi) << 16);
}
__device__ inline uint4 pack8f(const float* f) {
    uint4 o;
    o.x = pack2(f[0], f[1]); o.y = pack2(f[2], f[3]);
    o.z = pack2(f[4], f[5]); o.w = pack2(f[6], f[7]);
    return o;
}
__device__ inline void addrow(float* acc, uint4 r) {
    acc[0] += bflo(r.x); acc[1] += bfhi(r.x);
    acc[2] += bflo(r.y); acc[3] += bfhi(r.y);
    acc[4] += bflo(r.z); acc[5] += bfhi(r.z);
    acc[6] += bflo(r.w); acc[7] += bfhi(r.w);
}

struct P1 {
    unsigned int srt[ECH];   // 8 KB
    int off[NB];             // 3.1 KB
    int pos[NB];             // 3.1 KB
    int wsum[4];
};
struct P2 {
    unsigned short sorted[RAWCAP];          // 5 KB
    union {
        unsigned int raw[RAWCAP];           // 10 KB  (dead before Hs written)
        unsigned short Hs[64][HP];          // 17.4 KB
    } u;
    int cnt[64]; int off2[65]; int pos2[64];
    int rawpos;
};

// ===========================================================================
// One cooperative kernel, ZERO hot global atomics:
//  P1: per-block LDS counting sort of its 2048-edge chunk; write exact-offset
//      runs into fixed (bucket,chunk) 64B slices + coalesced hist row; then
//      grid-stride fp32->bf16 convert of E/W1/W2.   grid.sync.
//  P2: block = bucket: compact ragged slices (counts from hist column) into
//      LDS, sort by node-low6, gather-sum E rows, MFMA GEMM, fused epilogue.
// ===========================================================================
__global__ __launch_bounds__(256, 4) void mega(
    const float* __restrict__ E, const float* __restrict__ W1,
    const float* __restrict__ W2,
    const float* __restrict__ b1, const float* __restrict__ b2,
    const int* __restrict__ src, const int* __restrict__ dst, int n_edges,
    unsigned short* __restrict__ Ebf, unsigned short* __restrict__ W1b,
    unsigned short* __restrict__ W2b,
    int* __restrict__ hist, unsigned int* __restrict__ stag,
    int* __restrict__ ovf_cnt, int2* __restrict__ ovf,
    float* __restrict__ out)
{
    __shared__ union ShU { P1 p1; P2 p2; } sh;
    __shared__ int s_novf;

    cg::grid_group grid = cg::this_grid();
    const int tid = threadIdx.x;
    const int bid = blockIdx.x;
    const int gid = bid * 256 + tid;
    const int gsz = gridDim.x * 256;

    // ---------------- P1: bin my chunk (atomic-free placement) --------------
    {
        const int e0 = bid * ECH;
        const int m = min(ECH, n_edges - e0);
        int uu[EPT], vv[EPT];
        #pragma unroll
        for (int k = 0; k < EPT; ++k) {
            int i = tid + 256 * k;
            if (i < m) { uu[k] = src[e0 + i]; vv[k] = dst[e0 + i]; }
            else vv[k] = -1;
        }
        for (int b = tid; b < NB; b += 256) sh.p1.pos[b] = 0;
        __syncthreads();
        #pragma unroll
        for (int k = 0; k < EPT; ++k)
            if (vv[k] >= 0) atomicAdd(&sh.p1.pos[vv[k] >> 6], 1);
        __syncthreads();

        // write my hist row (counts), coalesced
        for (int b = tid; b < NB; b += 256)
            hist[(size_t)bid * NB + b] = sh.p1.pos[b];

        // exclusive scan pos -> off (thread covers 4 buckets)
        const int lane = tid & 63, w = tid >> 6;
        int b0 = tid * 4;
        int loc[4]; int s = 0;
        #pragma unroll
        for (int j = 0; j < 4; ++j) {
            int bb = b0 + j;
            int cv = (bb < NB) ? sh.p1.pos[bb] : 0;
            loc[j] = s; s += cv;
        }
        int incl = s;
        #pragma unroll
        for (int d = 1; d < 64; d <<= 1) {
            int t2 = __shfl_up(incl, d);
            if (lane >= d) incl += t2;
        }
        if (lane == 63) sh.p1.wsum[w] = incl;
        __syncthreads();
        int wbase = 0;
        for (int w2 = 0; w2 < w; ++w2) wbase += sh.p1.wsum[w2];
        int base = wbase + incl - s;
        #pragma unroll
        for (int j = 0; j < 4; ++j) {
            int bb = b0 + j;
            if (bb < NB) { sh.p1.off[bb] = base + loc[j]; sh.p1.pos[bb] = base + loc[j]; }
        }
        __syncthreads();

        #pragma unroll
        for (int k = 0; k < EPT; ++k) {
            if (vv[k] >= 0) {
                int p = atomicAdd(&sh.p1.pos[vv[k] >> 6], 1);
                sh.p1.srt[p] = (unsigned int)uu[k]
                             | ((unsigned int)(vv[k] & 63) << 16);
            }
        }
        __syncthreads();

        // flush runs to fixed slices — no global atomics
        for (int bb = tid; bb < NB; bb += 256) {
            int s0 = sh.p1.off[bb];
            int c = sh.p1.pos[bb] - s0;
            if (!c) continue;
            unsigned int* cell = stag + ((size_t)bb * NBLK + bid) * SLICE;
            int cw = c < SLICE ? c : SLICE;
            for (int k = 0; k < cw; ++k) cell[k] = sh.p1.srt[s0 + k];
            for (int k = SLICE; k < c; ++k) {            // ~never
                unsigned int r = sh.p1.srt[s0 + k];
                int oi = atomicAdd(ovf_cnt, 1);
                if (oi < OVCAP)
                    ovf[oi] = make_int2((int)(r & 0xffffu),
                                        bb * 64 + (int)((r >> 16) & 63));
            }
        }
    }

    // ---------------- P1b: convert E/W1/W2 fp32 -> bf16 ---------------------
    {
        const int NE8 = NN * DD / 8;          // 800000
        const int NW8 = DD * DD / 8;          // 2048
        const int NCV = NE8 + 2 * NW8;
        for (int t = gid; t < NCV; t += gsz) {
            const float* s2; unsigned short* d2; int idx;
            if (t < NE8)            { s2 = E;  d2 = Ebf; idx = t; }
            else if (t < NE8 + NW8) { s2 = W1; d2 = W1b; idx = t - NE8; }
            else                    { s2 = W2; d2 = W2b; idx = t - NE8 - NW8; }
            float4 a = ((const float4*)s2)[(size_t)idx * 2];
            float4 b = ((const float4*)s2)[(size_t)idx * 2 + 1];
            uint4 o;
            o.x = pack2(a.x, a.y); o.y = pack2(a.z, a.w);
            o.z = pack2(b.x, b.y); o.w = pack2(b.z, b.w);
            ((uint4*)d2)[idx] = o;
        }
    }

    grid.sync();

    // ---------------- P2: bucket = block --------------------------------
    const int b = bid;

    if (tid == 0) {
        sh.p2.rawpos = 0;
        int t = *ovf_cnt; s_novf = t < OVCAP ? t : OVCAP;
    }
    __syncthreads();

    // compact ragged slices into LDS raw[]
    for (int t = tid; t < NBLK; t += 256) {
        int c = hist[(size_t)t * NB + b];
        if (!c) continue;
        int cw = c < SLICE ? c : SLICE;
        int p = atomicAdd(&sh.p2.rawpos, cw);
        const unsigned int* cell = stag + ((size_t)b * NBLK + t) * SLICE;
        for (int k = 0; k < cw; ++k) {
            int q = p + k;
            if (q < RAWCAP) sh.p2.u.raw[q] = cell[k];
        }
    }
    __syncthreads();
    int rawlen = sh.p2.rawpos; rawlen = rawlen < RAWCAP ? rawlen : RAWCAP;

    // counting sort by node-low6
    if (tid < 64) sh.p2.cnt[tid] = 0;
    __syncthreads();
    for (int i = tid; i < rawlen; i += 256)
        atomicAdd(&sh.p2.cnt[(sh.p2.u.raw[i] >> 16) & 63], 1);
    __syncthreads();
    if (tid == 0) {
        int a = 0;
        for (int j = 0; j < 64; ++j) {
            sh.p2.off2[j] = a; sh.p2.pos2[j] = a; a += sh.p2.cnt[j];
        }
        sh.p2.off2[64] = a;
    }
    __syncthreads();
    for (int i = tid; i < rawlen; i += 256) {
        unsigned int r = sh.p2.u.raw[i];
        int p = atomicAdd(&sh.p2.pos2[(r >> 16) & 63], 1);
        sh.p2.sorted[p] = (unsigned short)(r & 0xffffu);
    }
    __syncthreads();
    const int novf = s_novf;

    // gather: 16 lanes per node x 16 nodes per pass, 4 passes
    {
        const int g = tid >> 4;
        const int c = tid & 15;
        const uint4* E4 = (const uint4*)Ebf;
        for (int p4 = 0; p4 < 4; ++p4) {
            int nl = p4 * 16 + g;
            int v = b * 64 + nl;
            if (v >= NN) continue;
            float acc[8] = {};
            int i = sh.p2.off2[nl], e1 = sh.p2.off2[nl + 1];
            for (; i + 8 <= e1; i += 8) {
                uint4 r0 = E4[(size_t)sh.p2.sorted[i]     * 16 + c];
                uint4 r1 = E4[(size_t)sh.p2.sorted[i + 1] * 16 + c];
                uint4 r2 = E4[(size_t)sh.p2.sorted[i + 2] * 16 + c];
                uint4 r3 = E4[(size_t)sh.p2.sorted[i + 3] * 16 + c];
                uint4 r4 = E4[(size_t)sh.p2.sorted[i + 4] * 16 + c];
                uint4 r5 = E4[(size_t)sh.p2.sorted[i + 5] * 16 + c];
                uint4 r6 = E4[(size_t)sh.p2.sorted[i + 6] * 16 + c];
                uint4 r7 = E4[(size_t)sh.p2.sorted[i + 7] * 16 + c];
                addrow(acc, r0); addrow(acc, r1); addrow(acc, r2); addrow(acc, r3);
                addrow(acc, r4); addrow(acc, r5); addrow(acc, r6); addrow(acc, r7);
            }
            for (; i + 2 <= e1; i += 2) {
                uint4 r0 = E4[(size_t)sh.p2.sorted[i]     * 16 + c];
                uint4 r1 = E4[(size_t)sh.p2.sorted[i + 1] * 16 + c];
                addrow(acc, r0); addrow(acc, r1);
            }
            if (i < e1) addrow(acc, E4[(size_t)sh.p2.sorted[i] * 16 + c]);

            if (novf > 0) {
                for (int k = 0; k < novf; ++k) {
                    int2 e = ovf[k];
                    if (e.y == v) addrow(acc, E4[(size_t)e.x * 16 + c]);
                }
            }
            *(uint4*)&sh.p2.u.Hs[nl][c * 8] = pack8f(acc);
        }
    }
    __syncthreads();

    // GEMM: wave w -> node rows w*16 .. w*16+15
    const int wave = tid >> 6;
    const int lane = tid & 63;
    const int v0 = b * 64 + wave * 16;
    if (v0 >= NN) return;
    const int m = lane & 15;
    const int quad = lane >> 4;

    bf16x8 aH[4], aE[4];
    const unsigned short* hrow = &sh.p2.u.Hs[wave * 16 + m][quad * 8];
    const unsigned short* erow = Ebf + (size_t)(v0 + m) * DD + quad * 8;
    #pragma unroll
    for (int ks = 0; ks < 4; ++ks) {
        bf16x8 h8 = *(const bf16x8*)(hrow + ks * 32);
        bf16x8 e8 = *(const bf16x8*)(erow + ks * 32);
        aH[ks] = h8;
        bf16x8 eh;
        #pragma unroll
        for (int j = 0; j < 8; ++j)
            eh[j] = (short)rnebf(sbf(h8[j]) * sbf(e8[j]));
        aE[ks] = eh;
    }

    #pragma unroll
    for (int jt = 0; jt < 8; ++jt) {
        const int j0 = jt * 16;
        const unsigned short* w1r = W1b + (size_t)(j0 + m) * DD + quad * 8;
        const unsigned short* w2r = W2b + (size_t)(j0 + m) * DD + quad * 8;
        f32x4 acc1 = {0.f, 0.f, 0.f, 0.f}, acc2 = {0.f, 0.f, 0.f, 0.f};
        #pragma unroll
        for (int ks = 0; ks < 4; ++ks) {
            bf16x8 bw1 = *(const bf16x8*)(w1r + ks * 32);
            bf16x8 bw2 = *(const bf16x8*)(w2r + ks * 32);
            acc1 = __builtin_amdgcn_mfma_f32_16x16x32_bf16(aH[ks], bw1, acc1, 0, 0, 0);
            acc2 = __builtin_amdgcn_mfma_f32_16x16x32_bf16(aE[ks], bw2, acc2, 0, 0, 0);
        }
        const float bb1 = b1[j0 + m], bb2 = b2[j0 + m];
        #pragma unroll
        for (int i = 0; i < 4; ++i) {
            int row = v0 + quad * 4 + i;
            if (row < NN) {
                float x1 = acc1[i] + bb1; x1 = x1 > 0.f ? x1 : SLOPE * x1;
                float x2 = acc2[i] + bb2; x2 = x2 > 0.f ? x2 : SLOPE * x2;
                out[(size_t)row * DD + j0 + m] = x1 + x2;
            }
        }
    }
}

// ===================== fallback: round-7 3-dispatch path ====================
__global__ __launch_bounds__(BST) void convert_bin(
    const float* __restrict__ E, const float* __restrict__ W1,
    const float* __restrict__ W2, const int* __restrict__ src,
    const int* __restrict__ dst, unsigned short* __restrict__ Ebf,
    unsigned short* __restrict__ W1b, unsigned short* __restrict__ W2b,
    int* __restrict__ gtail, unsigned int* __restrict__ stag,
    int* __restrict__ ovf_cnt, int2* __restrict__ ovf,
    int n_edges, int nbin)
{
    const int tid = threadIdx.x;
    if (blockIdx.x >= nbin) {
        const int NE8 = NN * DD / 8;
        const int NW8 = DD * DD / 8;
        int t = (blockIdx.x - nbin) * BST + tid;
        const float* s; unsigned short* d; int idx;
        if (t < NE8)                { s = E;  d = Ebf; idx = t; }
        else if (t < NE8 + NW8)     { s = W1; d = W1b; idx = t - NE8; }
        else if (t < NE8 + 2 * NW8) { s = W2; d = W2b; idx = t - NE8 - NW8; }
        else return;
        float4 a = ((const float4*)s)[(size_t)idx * 2];
        float4 b = ((const float4*)s)[(size_t)idx * 2 + 1];
        uint4 o;
        o.x = pack2(a.x, a.y); o.y = pack2(a.z, a.w);
        o.z = pack2(b.x, b.y); o.w = pack2(b.z, b.w);
        ((uint4*)d)[idx] = o;
        return;
    }
    __shared__ unsigned int srt[FECH];
    __shared__ int cnt[NB], off[NB], pos[NB];
    __shared__ int wsum[BST / 64];
    const int e0 = blockIdx.x * FECH;
    const int m = min(FECH, n_edges - e0);
    for (int b = tid; b < NB; b += BST) cnt[b] = 0;
    __syncthreads();
    for (int i = tid; i < m; i += BST)
        atomicAdd(&cnt[dst[e0 + i] >> 6], 1);
    __syncthreads();
    const int lane = tid & 63, w = tid >> 6;
    int b0 = tid * PB2;
    int loc[PB2]; int s = 0;
    #pragma unroll
    for (int j = 0; j < PB2; ++j) {
        int bb = b0 + j;
        int cv = (bb < NB) ? cnt[bb] : 0;
        loc[j] = s; s += cv;
    }
    int incl = s;
    #pragma unroll
    for (int d = 1; d < 64; d <<= 1) {
        int t2 = __shfl_up(incl, d);
        if (lane >= d) incl += t2;
    }
    if (lane == 63) wsum[w] = incl;
    __syncthreads();
    int wbase = 0;
    for (int w2 = 0; w2 < w; ++w2) wbase += wsum[w2];
    int base = wbase + incl - s;
    #pragma unroll
    for (int j = 0; j < PB2; ++j) {
        int bb = b0 + j;
        if (bb < NB) { off[bb] = base + loc[j]; pos[bb] = base + loc[j]; }
    }
    __syncthreads();
    for (int i = tid; i < m; i += BST) {
        int v = dst[e0 + i];
        int u = src[e0 + i];
        int p = atomicAdd(&pos[v >> 6], 1);
        srt[p] = (unsigned int)u | ((unsigned int)(v & 63) << 16);
    }
    __syncthreads();
    for (int bb = tid; bb < NB; bb += BST) {
        int c = cnt[bb];
        if (!c) continue;
        int g = atomicAdd(&gtail[bb], c);
        int s0 = off[bb];
        unsigned int* dstp = stag + (size_t)bb * BCAP;
        for (int k = 0; k < c; ++k) {
            int gp = g + k;
            unsigned int r = srt[s0 + k];
            if (gp < BCAP) dstp[gp] = r;
            else {
                int oi = atomicAdd(ovf_cnt, 1);
                if (oi < OVCAP)
                    ovf[oi] = make_int2((int)(r & 0xffffu),
                                        bb * 64 + (int)((r >> 16) & 63));
            }
        }
    }
}

__global__ __launch_bounds__(256) void bucket_fused(
    const unsigned short* __restrict__ Ebf, const int* __restrict__ gtail,
    const unsigned int* __restrict__ stag, const int* __restrict__ ovf_cnt,
    const int2* __restrict__ ovf,
    const unsigned short* __restrict__ W1b, const unsigned short* __restrict__ W2b,
    const float* __restrict__ b1, const float* __restrict__ b2,
    float* __restrict__ out)
{
    __shared__ unsigned short sorted[BCAP];
    __shared__ unsigned short Hs[64][HP];
    __shared__ int cnt[64], off[65], pos[64];
    __shared__ int s_novf;
    const int b = blockIdx.x;
    const int tid = threadIdx.x;
    int len = gtail[b]; len = len < BCAP ? len : BCAP;
    const unsigned int* seg = stag + (size_t)b * BCAP;
    if (tid == 0) { int t = *ovf_cnt; s_novf = t < OVCAP ? t : OVCAP; }
    if (tid < 64) cnt[tid] = 0;
    __syncthreads();
    for (int i = tid; i < len; i += 256)
        atomicAdd(&cnt[(seg[i] >> 16) & 63], 1);
    __syncthreads();
    if (tid == 0) {
        int a = 0;
        for (int j = 0; j < 64; ++j) { off[j] = a; pos[j] = a; a += cnt[j]; }
        off[64] = a;
    }
    __syncthreads();
    for (int i = tid; i < len; i += 256) {
        unsigned int r = seg[i];
        int p = atomicAdd(&pos[(r >> 16) & 63], 1);
        sorted[p] = (unsigned short)(r & 0xffffu);
    }
    __syncthreads();
    const int novf = s_novf;
    const int g = tid >> 4;
    const int c = tid & 15;
    const uint4* E4 = (const uint4*)Ebf;
    for (int p4 = 0; p4 < 4; ++p4) {
        int nl = p4 * 16 + g;
        int v = b * 64 + nl;
        if (v >= NN) continue;
        float acc[8] = {};
        int i = off[nl], e1 = off[nl + 1];
        for (; i + 8 <= e1; i += 8) {
            uint4 r0 = E4[(size_t)sorted[i]     * 16 + c];
            uint4 r1 = E4[(size_t)sorted[i + 1] * 16 + c];
            uint4 r2 = E4[(size_t)sorted[i + 2] * 16 + c];
            uint4 r3 = E4[(size_t)sorted[i + 3] * 16 + c];
            uint4 r4 = E4[(size_t)sorted[i + 4] * 16 + c];
            uint4 r5 = E4[(size_t)sorted[i + 5] * 16 + c];
            uint4 r6 = E4[(size_t)sorted[i + 6] * 16 + c];
            uint4 r7 = E4[(size_t)sorted[i + 7] * 16 + c];
            addrow(acc, r0); addrow(acc, r1); addrow(acc, r2); addrow(acc, r3);
            addrow(acc, r4); addrow(acc, r5); addrow(acc, r6); addrow(acc, r7);
        }
        for (; i + 2 <= e1; i += 2) {
            uint4 r0 = E4[(size_t)sorted[i]     * 16 + c];
            uint4 r1 = E4[(size_t)sorted[i + 1] * 16 + c];
            addrow(acc, r0); addrow(acc, r1);
        }
        if (i < e1) addrow(acc, E4[(size_t)sorted[i] * 16 + c]);
        if (novf > 0) {
            for (int k = 0; k < novf; ++k) {
                int2 e = ovf[k];
                if (e.y == v) addrow(acc, E4[(size_t)e.x * 16 + c]);
            }
        }
        *(uint4*)&Hs[nl][c * 8] = pack8f(acc);
    }
    __syncthreads();
    const int wave = tid >> 6;
    const int lane = tid & 63;
    const int v0 = b * 64 + wave * 16;
    if (v0 >= NN) return;
    const int m = lane & 15;
    const int quad = lane >> 4;
    bf16x8 aH[4], aE[4];
    const unsigned short* hrow = &Hs[wave * 16 + m][quad * 8];
    const unsigned short* erow = Ebf + (size_t)(v0 + m) * DD + quad * 8;
    #pragma unroll
    for (int ks = 0; ks < 4; ++ks) {
        bf16x8 h8 = *(const bf16x8*)(hrow + ks * 32);
        bf16x8 e8 = *(const bf16x8*)(erow + ks * 32);
        aH[ks] = h8;
        bf16x8 eh;
        #pragma unroll
        for (int j = 0; j < 8; ++j)
            eh[j] = (short)rnebf(sbf(h8[j]) * sbf(e8[j]));
        aE[ks] = eh;
    }
    #pragma unroll
    for (int jt = 0; jt < 8; ++jt) {
        const int j0 = jt * 16;
        const unsigned short* w1r = W1b + (size_t)(j0 + m) * DD + quad * 8;
        const unsigned short* w2r = W2b + (size_t)(j0 + m) * DD + quad * 8;
        f32x4 acc1 = {0.f, 0.f, 0.f, 0.f}, acc2 = {0.f, 0.f, 0.f, 0.f};
        #pragma unroll
        for (int ks = 0; ks < 4; ++ks) {
            bf16x8 bw1 = *(const bf16x8*)(w1r + ks * 32);
            bf16x8 bw2 = *(const bf16x8*)(w2r + ks * 32);
            acc1 = __builtin_amdgcn_mfma_f32_16x16x32_bf16(aH[ks], bw1, acc1, 0, 0, 0);
            acc2 = __builtin_amdgcn_mfma_f32_16x16x32_bf16(aE[ks], bw2, acc2, 0, 0, 0);
        }
        const float bb1 = b1[j0 + m], bb2 = b2[j0 + m];
        #pragma unroll
        for (int i = 0; i < 4; ++i) {
            int row = v0 + quad * 4 + i;
            if (row < NN) {
                float x1 = acc1[i] + bb1; x1 = x1 > 0.f ? x1 : SLOPE * x1;
                float x2 = acc2[i] + bb2; x2 = x2 > 0.f ? x2 : SLOPE * x2;
                out[(size_t)row * DD + j0 + m] = x1 + x2;
            }
        }
    }
}

// ============== minimal fallback (ws too small): fp32 atomics ==============
__global__ __launch_bounds__(256) void scatter_add(
    const float* __restrict__ E, const int* __restrict__ src,
    const int* __restrict__ dst, float* __restrict__ H, int n_edges)
{
    int t = blockIdx.x * 256 + threadIdx.x;
    int e = t >> 5;
    if (e >= n_edges) return;
    int c = t & 31;
    float4 a = ((const float4*)E)[(size_t)src[e] * 32 + c];
    float* hp = H + (size_t)dst[e] * DD + c * 4;
    atomicAdd(hp + 0, a.x); atomicAdd(hp + 1, a.y);
    atomicAdd(hp + 2, a.z); atomicAdd(hp + 3, a.w);
}

__global__ __launch_bounds__(256) void fused_mlp(
    const float* __restrict__ E, const float* __restrict__ H,
    const float* __restrict__ W1, const float* __restrict__ b1,
    const float* __restrict__ W2, const float* __restrict__ b2,
    float* __restrict__ out)
{
    __shared__ float Hsf[32][DD];
    __shared__ float EHs[32][DD];
    __shared__ float W1s[DD][20];
    __shared__ float W2s[DD][20];
    const int tid = threadIdx.x;
    const int v0 = blockIdx.x * 32;
    const int nvalid = min(32, NN - v0);
    for (int i = 0; i < 4; ++i) {
        int f = tid + 256 * i;
        int n = f >> 5, c = f & 31;
        float4 h = make_float4(0.f, 0.f, 0.f, 0.f);
        float4 eh = h;
        if (n < nvalid) {
            h = ((const float4*)H)[(size_t)(v0 + n) * 32 + c];
            float4 e4 = ((const float4*)E)[(size_t)(v0 + n) * 32 + c];
            eh = make_float4(e4.x * h.x, e4.y * h.y, e4.z * h.z, e4.w * h.w);
        }
        *((float4*)&Hsf[n][c * 4]) = h;
        *((float4*)&EHs[n][c * 4]) = eh;
    }
    const int jg = tid & 63;
    const int n0 = (tid >> 6) * 8;
    float acc1a[8] = {}, acc1b[8] = {}, acc2a[8] = {}, acc2b[8] = {};
    for (int t8 = 0; t8 < 8; ++t8) {
        const int k0 = t8 * 16;
        __syncthreads();
        for (int i = 0; i < 8; ++i) {
            int f = tid + 256 * i;
            int j = f >> 4, kk = f & 15;
            W1s[j][kk] = W1[j * DD + k0 + kk];
            W2s[j][kk] = W2[j * DD + k0 + kk];
        }
        __syncthreads();
        for (int c = 0; c < 4; ++c) {
            float4 w1a = *((const float4*)&W1s[jg][c * 4]);
            float4 w1b = *((const float4*)&W1s[jg + 64][c * 4]);
            float4 w2a = *((const float4*)&W2s[jg][c * 4]);
            float4 w2b = *((const float4*)&W2s[jg + 64][c * 4]);
            const int kk = k0 + c * 4;
            for (int n = 0; n < 8; ++n) {
                float4 h = *((const float4*)&Hsf[n0 + n][kk]);
                float4 eh = *((const float4*)&EHs[n0 + n][kk]);
                acc1a[n] += h.x * w1a.x + h.y * w1a.y + h.z * w1a.z + h.w * w1a.w;
                acc1b[n] += h.x * w1b.x + h.y * w1b.y + h.z * w1b.z + h.w * w1b.w;
                acc2a[n] += eh.x * w2a.x + eh.y * w2a.y + eh.z * w2a.z + eh.w * w2a.w;
                acc2b[n] += eh.x * w2b.x + eh.y * w2b.y + eh.z * w2b.z + eh.w * w2b.w;
            }
        }
    }
    const float b1a = b1[jg], b1b = b1[jg + 64];
    const float b2a = b2[jg], b2b = b2[jg + 64];
    for (int n = 0; n < 8; ++n) {
        if (n0 + n < nvalid) {
            const int v = v0 + n0 + n;
            float x1 = acc1a[n] + b1a; x1 = x1 > 0.f ? x1 : SLOPE * x1;
            float x2 = acc2a[n] + b2a; x2 = x2 > 0.f ? x2 : SLOPE * x2;
            out[(size_t)v * DD + jg] = x1 + x2;
            float y1 = acc1b[n] + b1b; y1 = y1 > 0.f ? y1 : SLOPE * y1;
            float y2 = acc2b[n] + b2b; y2 = y2 > 0.f ? y2 : SLOPE * y2;
            out[(size_t)v * DD + jg + 64] = y1 + y2;
        }
    }
}
// ===========================================================================

extern "C" void kernel_launch(void* const* d_in, const int* in_sizes, int n_in,
                              void* d_out, int out_size, void* d_ws, size_t ws_size,
                              hipStream_t stream)
{
    const float* E  = (const float*)d_in[0];
    const float* W1 = (const float*)d_in[1];
    const float* b1 = (const float*)d_in[2];
    const float* W2 = (const float*)d_in[3];
    const float* b2 = (const float*)d_in[4];
    const int* src  = (const int*)d_in[5];
    const int* dst  = (const int*)d_in[6];
    float* out = (float*)d_out;
    int n_edges = in_sizes[5];

    char* ws = (char*)d_ws;
    auto al = [](size_t x) { return (x + 255) & ~(size_t)255; };

    // ---- mega (exact-offset) layout: ~54.5 MB ----
    const size_t m_hist = 0;                                    // NBLK*NB*4
    const size_t m_ovfc = al((size_t)NBLK * NB * 4);
    const size_t m_ovf  = al(m_ovfc + 4);
    const size_t m_stag = al(m_ovf + (size_t)OVCAP * 8);
    const size_t m_Ebf  = al(m_stag + (size_t)NB * NBLK * SLICE * 4);
    const size_t m_W1b  = al(m_Ebf + (size_t)NN * DD * 2);
    const size_t m_W2b  = al(m_W1b + (size_t)DD * DD * 2);
    const size_t need_mega = m_W2b + (size_t)DD * DD * 2;

    if (ws_size >= need_mega) {
        int dev = 0, coop = 0;
        hipGetDevice(&dev);
        hipDeviceGetAttribute(&coop, hipDeviceAttributeCooperativeLaunch, dev);
        if (coop) {
            int*  histp   = (int*)(ws + m_hist);
            int*  ovf_cnt = (int*)(ws + m_ovfc);
            int2* ovf     = (int2*)(ws + m_ovf);
            unsigned int*   stag = (unsigned int*)(ws + m_stag);
            unsigned short* Ebf  = (unsigned short*)(ws + m_Ebf);
            unsigned short* W1b  = (unsigned short*)(ws + m_W1b);
            unsigned short* W2b  = (unsigned short*)(ws + m_W2b);

            hipMemsetAsync(ovf_cnt, 0, 4, stream);
            void* args[] = {
                (void*)&E, (void*)&W1, (void*)&W2, (void*)&b1, (void*)&b2,
                (void*)&src, (void*)&dst, (void*)&n_edges,
                (void*)&Ebf, (void*)&W1b, (void*)&W2b,
                (void*)&histp, (void*)&stag, (void*)&ovf_cnt, (void*)&ovf,
                (void*)&out
            };
            hipError_t err = hipLaunchCooperativeKernel(
                (const void*)mega, dim3(NB), dim3(256), args, 0, stream);
            if (err == hipSuccess) return;
        }
    }

    // ---- fallback: round-7 3-dispatch path (~21 MB) ----
    const size_t off_tail = 0;
    const size_t off_ovfc = (size_t)NB * 4;
    const size_t off_ovf  = al(off_ovfc + 4);
    const size_t off_stag = al(off_ovf + (size_t)OVCAP * 8);
    const size_t off_Ebf  = al(off_stag + (size_t)NB * BCAP * 4);
    const size_t off_W1b  = al(off_Ebf + (size_t)NN * DD * 2);
    const size_t off_W2b  = al(off_W1b + (size_t)DD * DD * 2);
    const size_t need_bf  = off_W2b + (size_t)DD * DD * 2;

    if (ws_size >= need_bf) {
        int*  gtail   = (int*)(ws + off_tail);
        int*  ovf_cnt = (int*)(ws + off_ovfc);
        int2* ovf     = (int2*)(ws + off_ovf);
        unsigned int*   stag = (unsigned int*)(ws + off_stag);
        unsigned short* Ebf  = (unsigned short*)(ws + off_Ebf);
        unsigned short* W1b  = (unsigned short*)(ws + off_W1b);
        unsigned short* W2b  = (unsigned short*)(ws + off_W2b);

        const int nbin = (n_edges + FECH - 1) / FECH;
        const int ncv  = NN * DD / 8 + 2 * (DD * DD / 8);
        const int ncvb = (ncv + BST - 1) / BST;
        hipMemsetAsync(ws, 0, off_ovf, stream);
        convert_bin<<<nbin + ncvb, BST, 0, stream>>>(
            E, W1, W2, src, dst, Ebf, W1b, W2b,
            gtail, stag, ovf_cnt, ovf, n_edges, nbin);
        bucket_fused<<<NB, 256, 0, stream>>>(
            Ebf, gtail, stag, ovf_cnt, ovf, W1b, W2b, b1, b2, out);
        return;
    }

    // last resort: fp32 atomics
    const size_t hbytes = (size_t)NN * DD * sizeof(float);
    float* H = (ws_size >= hbytes) ? (float*)ws : out;
    hipMemsetAsync(H, 0, hbytes, stream);
    scatter_add<<<((n_edges * 32) + 255) / 256, 256, 0, stream>>>(
        E, src, dst, H, n_edges);
    fused_mlp<<<(NN + 31) / 32, 256, 0, stream>>>(E, H, W1, b1, W2, b2, out);
}

// Round 10
// 207.843 us; speedup vs baseline: 1.7302x; 1.5560x over previous
//
#include <hip/hip_runtime.h>

#define NN 50000
#define DD 128
#define SLOPE 0.01f
#define NB 782        // buckets of 64 nodes: bucket = v>>6
#define BCAP 2560     // per-bucket cap; mean 2046, sigma 45 -> +11 sigma
#define FECH 6144     // edges per bin block
#define BST 512       // convert_bin block threads
#define PB2 2         // buckets per thread in prefix scan (512*2 >= 782)
#define OVCAP 8192
#define HP 136        // Hs row pitch (bf16): 272B rows -> 2-way-only bank alias

using bf16x8 = __attribute__((ext_vector_type(8))) short;
using f32x4  = __attribute__((ext_vector_type(4))) float;

// ---------------- bf16 helpers (RNE) ----------------
__device__ inline float bflo(unsigned int w) { return __uint_as_float(w << 16); }
__device__ inline float bfhi(unsigned int w) { return __uint_as_float(w & 0xffff0000u); }
__device__ inline float sbf(short s) {
    return __uint_as_float(((unsigned int)(unsigned short)s) << 16);
}
__device__ inline unsigned int rnebf(float f) {
    unsigned int u = __float_as_uint(f);
    return (u + 0x7fffu + ((u >> 16) & 1u)) >> 16;
}
__device__ inline unsigned int pack2(float lo, float hi) {
    return rnebf(lo) | (rnebf(hi) << 16);
}
__device__ inline uint4 pack8f(const float* f) {
    uint4 o;
    o.x = pack2(f[0], f[1]); o.y = pack2(f[2], f[3]);
    o.z = pack2(f[4], f[5]); o.w = pack2(f[6], f[7]);
    return o;
}
__device__ inline void addrow(float* acc, uint4 r) {
    acc[0] += bflo(r.x); acc[1] += bfhi(r.x);
    acc[2] += bflo(r.y); acc[3] += bfhi(r.y);
    acc[4] += bflo(r.z); acc[5] += bfhi(r.z);
    acc[6] += bflo(r.w); acc[7] += bfhi(r.w);
}

// ---------------------------------------------------------------------------
// Fused: blocks [0,nbin) LDS-counting-sort FECH edges each and flush runs with
// one global atomic per (block,bucket); blocks [nbin,..) convert fp32->bf16.
// ---------------------------------------------------------------------------
__global__ __launch_bounds__(BST) void convert_bin(
    const float* __restrict__ E, const float* __restrict__ W1,
    const float* __restrict__ W2, const int* __restrict__ src,
    const int* __restrict__ dst, unsigned short* __restrict__ Ebf,
    unsigned short* __restrict__ W1b, unsigned short* __restrict__ W2b,
    int* __restrict__ gtail, unsigned int* __restrict__ stag,
    int* __restrict__ ovf_cnt, int2* __restrict__ ovf,
    int n_edges, int nbin)
{
    const int tid = threadIdx.x;
    if (blockIdx.x >= nbin) {
        const int NE8 = NN * DD / 8;
        const int NW8 = DD * DD / 8;
        int t = (blockIdx.x - nbin) * BST + tid;
        const float* s; unsigned short* d; int idx;
        if (t < NE8)                { s = E;  d = Ebf; idx = t; }
        else if (t < NE8 + NW8)     { s = W1; d = W1b; idx = t - NE8; }
        else if (t < NE8 + 2 * NW8) { s = W2; d = W2b; idx = t - NE8 - NW8; }
        else return;
        float4 a = ((const float4*)s)[(size_t)idx * 2];
        float4 b = ((const float4*)s)[(size_t)idx * 2 + 1];
        uint4 o;
        o.x = pack2(a.x, a.y); o.y = pack2(a.z, a.w);
        o.z = pack2(b.x, b.y); o.w = pack2(b.z, b.w);
        ((uint4*)d)[idx] = o;
        return;
    }
    __shared__ unsigned int srt[FECH];     // 24 KB
    __shared__ int cnt[NB], off[NB], pos[NB];
    __shared__ int wsum[BST / 64];
    const int e0 = blockIdx.x * FECH;
    const int m = min(FECH, n_edges - e0);
    for (int b = tid; b < NB; b += BST) cnt[b] = 0;
    __syncthreads();
    for (int i = tid; i < m; i += BST)
        atomicAdd(&cnt[dst[e0 + i] >> 6], 1);
    __syncthreads();
    const int lane = tid & 63, w = tid >> 6;
    int b0 = tid * PB2;
    int loc[PB2]; int s = 0;
    #pragma unroll
    for (int j = 0; j < PB2; ++j) {
        int bb = b0 + j;
        int cv = (bb < NB) ? cnt[bb] : 0;
        loc[j] = s; s += cv;
    }
    int incl = s;
    #pragma unroll
    for (int d = 1; d < 64; d <<= 1) {
        int t2 = __shfl_up(incl, d);
        if (lane >= d) incl += t2;
    }
    if (lane == 63) wsum[w] = incl;
    __syncthreads();
    int wbase = 0;
    for (int w2 = 0; w2 < w; ++w2) wbase += wsum[w2];
    int base = wbase + incl - s;
    #pragma unroll
    for (int j = 0; j < PB2; ++j) {
        int bb = b0 + j;
        if (bb < NB) { off[bb] = base + loc[j]; pos[bb] = base + loc[j]; }
    }
    __syncthreads();
    for (int i = tid; i < m; i += BST) {
        int v = dst[e0 + i];
        int u = src[e0 + i];
        int p = atomicAdd(&pos[v >> 6], 1);
        srt[p] = (unsigned int)u | ((unsigned int)(v & 63) << 16);
    }
    __syncthreads();
    for (int bb = tid; bb < NB; bb += BST) {
        int c = cnt[bb];
        if (!c) continue;
        int g = atomicAdd(&gtail[bb], c);
        int s0 = off[bb];
        unsigned int* dstp = stag + (size_t)bb * BCAP;
        for (int k = 0; k < c; ++k) {
            int gp = g + k;
            unsigned int r = srt[s0 + k];
            if (gp < BCAP) dstp[gp] = r;
            else {
                int oi = atomicAdd(ovf_cnt, 1);
                if (oi < OVCAP)
                    ovf[oi] = make_int2((int)(r & 0xffffu),
                                        bb * 64 + (int)((r >> 16) & 63));
            }
        }
    }
}

// ---------------------------------------------------------------------------
// Fused gather + GEMM, one block per bucket (64 nodes).
// Gather runs in 4 COLUMN-QUARTER passes: pass q touches only bytes
// [q*64, q*64+64) of each E row -> grid-wide working set 3.2 MB per pass,
// fits every XCD's 4 MiB L2 (blocks are co-resident & phase-aligned).
// Thread (nl=tid>>2, c4=tid&3): wave w gathers exactly rows [w*16,(w+1)*16),
// the same rows its GEMM consumes -> no barrier between gather and GEMM.
// ---------------------------------------------------------------------------
__global__ __launch_bounds__(256) void bucket_fused(
    const unsigned short* __restrict__ Ebf, const int* __restrict__ gtail,
    const unsigned int* __restrict__ stag, const int* __restrict__ ovf_cnt,
    const int2* __restrict__ ovf,
    const unsigned short* __restrict__ W1b, const unsigned short* __restrict__ W2b,
    const float* __restrict__ b1, const float* __restrict__ b2,
    float* __restrict__ out)
{
    __shared__ unsigned short sorted[BCAP];       // 5 KB
    __shared__ unsigned short Hs[64][HP];         // 17 KB
    __shared__ int cnt[64], off[65], pos[64];
    __shared__ int s_novf;

    const int b = blockIdx.x;
    const int tid = threadIdx.x;
    int len = gtail[b]; len = len < BCAP ? len : BCAP;
    const unsigned int* seg = stag + (size_t)b * BCAP;

    if (tid == 0) { int t = *ovf_cnt; s_novf = t < OVCAP ? t : OVCAP; }
    if (tid < 64) cnt[tid] = 0;
    __syncthreads();
    for (int i = tid; i < len; i += 256)
        atomicAdd(&cnt[(seg[i] >> 16) & 63], 1);
    __syncthreads();
    if (tid == 0) {
        int a = 0;
        for (int j = 0; j < 64; ++j) { off[j] = a; pos[j] = a; a += cnt[j]; }
        off[64] = a;
    }
    __syncthreads();
    for (int i = tid; i < len; i += 256) {
        unsigned int r = seg[i];
        int p = atomicAdd(&pos[(r >> 16) & 63], 1);
        sorted[p] = (unsigned short)(r & 0xffffu);
    }
    __syncthreads();
    const int novf = s_novf;

    // ---- gather: thread owns (node nl, 16B chunk c4) across 4 column passes
    const int nl = tid >> 2;          // 0..63  (wave w -> nl in [w*16,w*16+16))
    const int c4 = tid & 3;
    const int vnode = b * 64 + nl;
    const uint4* E4 = (const uint4*)Ebf;
    const int i0 = off[nl], i1 = off[nl + 1];

    #pragma unroll
    for (int q = 0; q < 4; ++q) {
        const int ch = q * 4 + c4;    // uint4 index within row, 0..15
        float acc[8] = {};
        if (vnode < NN) {
            int i = i0;
            for (; i + 8 <= i1; i += 8) {
                uint4 r0 = E4[(size_t)sorted[i]     * 16 + ch];
                uint4 r1 = E4[(size_t)sorted[i + 1] * 16 + ch];
                uint4 r2 = E4[(size_t)sorted[i + 2] * 16 + ch];
                uint4 r3 = E4[(size_t)sorted[i + 3] * 16 + ch];
                uint4 r4 = E4[(size_t)sorted[i + 4] * 16 + ch];
                uint4 r5 = E4[(size_t)sorted[i + 5] * 16 + ch];
                uint4 r6 = E4[(size_t)sorted[i + 6] * 16 + ch];
                uint4 r7 = E4[(size_t)sorted[i + 7] * 16 + ch];
                addrow(acc, r0); addrow(acc, r1); addrow(acc, r2); addrow(acc, r3);
                addrow(acc, r4); addrow(acc, r5); addrow(acc, r6); addrow(acc, r7);
            }
            for (; i + 2 <= i1; i += 2) {
                uint4 r0 = E4[(size_t)sorted[i]     * 16 + ch];
                uint4 r1 = E4[(size_t)sorted[i + 1] * 16 + ch];
                addrow(acc, r0); addrow(acc, r1);
            }
            if (i < i1) addrow(acc, E4[(size_t)sorted[i] * 16 + ch]);

            if (novf > 0) {                  // rare path: fold overflow edges
                for (int k = 0; k < novf; ++k) {
                    int2 e = ovf[k];
                    if (e.y == vnode) addrow(acc, E4[(size_t)e.x * 16 + ch]);
                }
            }
            *(uint4*)&Hs[nl][ch * 8] = pack8f(acc);
        }
    }
    // NO __syncthreads: wave w wrote exactly the Hs rows its GEMM reads.

    // ---- GEMM: wave w -> node rows w*16 .. w*16+15 ----
    const int wave = tid >> 6;
    const int lane = tid & 63;
    const int v0 = b * 64 + wave * 16;
    if (v0 >= NN) return;
    const int m = lane & 15;
    const int quad = lane >> 4;

    bf16x8 aH[4], aE[4];
    const unsigned short* hrow = &Hs[wave * 16 + m][quad * 8];
    const unsigned short* erow = Ebf + (size_t)(v0 + m) * DD + quad * 8;
    #pragma unroll
    for (int ks = 0; ks < 4; ++ks) {
        bf16x8 h8 = *(const bf16x8*)(hrow + ks * 32);
        bf16x8 e8 = *(const bf16x8*)(erow + ks * 32);
        aH[ks] = h8;
        bf16x8 eh;
        #pragma unroll
        for (int j = 0; j < 8; ++j)
            eh[j] = (short)rnebf(sbf(h8[j]) * sbf(e8[j]));
        aE[ks] = eh;
    }

    #pragma unroll
    for (int jt = 0; jt < 8; ++jt) {
        const int j0 = jt * 16;
        const unsigned short* w1r = W1b + (size_t)(j0 + m) * DD + quad * 8;
        const unsigned short* w2r = W2b + (size_t)(j0 + m) * DD + quad * 8;
        f32x4 acc1 = {0.f, 0.f, 0.f, 0.f}, acc2 = {0.f, 0.f, 0.f, 0.f};
        #pragma unroll
        for (int ks = 0; ks < 4; ++ks) {
            bf16x8 bw1 = *(const bf16x8*)(w1r + ks * 32);
            bf16x8 bw2 = *(const bf16x8*)(w2r + ks * 32);
            acc1 = __builtin_amdgcn_mfma_f32_16x16x32_bf16(aH[ks], bw1, acc1, 0, 0, 0);
            acc2 = __builtin_amdgcn_mfma_f32_16x16x32_bf16(aE[ks], bw2, acc2, 0, 0, 0);
        }
        const float bb1 = b1[j0 + m], bb2 = b2[j0 + m];
        #pragma unroll
        for (int i = 0; i < 4; ++i) {
            int row = v0 + quad * 4 + i;
            if (row < NN) {
                float x1 = acc1[i] + bb1; x1 = x1 > 0.f ? x1 : SLOPE * x1;
                float x2 = acc2[i] + bb2; x2 = x2 > 0.f ? x2 : SLOPE * x2;
                out[(size_t)row * DD + j0 + m] = x1 + x2;
            }
        }
    }
}

// ============== minimal fallback (ws too small): fp32 atomics ==============
__global__ __launch_bounds__(256) void scatter_add(
    const float* __restrict__ E, const int* __restrict__ src,
    const int* __restrict__ dst, float* __restrict__ H, int n_edges)
{
    int t = blockIdx.x * 256 + threadIdx.x;
    int e = t >> 5;
    if (e >= n_edges) return;
    int c = t & 31;
    float4 a = ((const float4*)E)[(size_t)src[e] * 32 + c];
    float* hp = H + (size_t)dst[e] * DD + c * 4;
    atomicAdd(hp + 0, a.x); atomicAdd(hp + 1, a.y);
    atomicAdd(hp + 2, a.z); atomicAdd(hp + 3, a.w);
}

__global__ __launch_bounds__(256) void fused_mlp(
    const float* __restrict__ E, const float* __restrict__ H,
    const float* __restrict__ W1, const float* __restrict__ b1,
    const float* __restrict__ W2, const float* __restrict__ b2,
    float* __restrict__ out)
{
    __shared__ float Hsf[32][DD];
    __shared__ float EHs[32][DD];
    __shared__ float W1s[DD][20];
    __shared__ float W2s[DD][20];
    const int tid = threadIdx.x;
    const int v0 = blockIdx.x * 32;
    const int nvalid = min(32, NN - v0);
    for (int i = 0; i < 4; ++i) {
        int f = tid + 256 * i;
        int n = f >> 5, c = f & 31;
        float4 h = make_float4(0.f, 0.f, 0.f, 0.f);
        float4 eh = h;
        if (n < nvalid) {
            h = ((const float4*)H)[(size_t)(v0 + n) * 32 + c];
            float4 e4 = ((const float4*)E)[(size_t)(v0 + n) * 32 + c];
            eh = make_float4(e4.x * h.x, e4.y * h.y, e4.z * h.z, e4.w * h.w);
        }
        *((float4*)&Hsf[n][c * 4]) = h;
        *((float4*)&EHs[n][c * 4]) = eh;
    }
    const int jg = tid & 63;
    const int n0 = (tid >> 6) * 8;
    float acc1a[8] = {}, acc1b[8] = {}, acc2a[8] = {}, acc2b[8] = {};
    for (int t8 = 0; t8 < 8; ++t8) {
        const int k0 = t8 * 16;
        __syncthreads();
        for (int i = 0; i < 8; ++i) {
            int f = tid + 256 * i;
            int j = f >> 4, kk = f & 15;
            W1s[j][kk] = W1[j * DD + k0 + kk];
            W2s[j][kk] = W2[j * DD + k0 + kk];
        }
        __syncthreads();
        for (int c = 0; c < 4; ++c) {
            float4 w1a = *((const float4*)&W1s[jg][c * 4]);
            float4 w1b = *((const float4*)&W1s[jg + 64][c * 4]);
            float4 w2a = *((const float4*)&W2s[jg][c * 4]);
            float4 w2b = *((const float4*)&W2s[jg + 64][c * 4]);
            const int kk = k0 + c * 4;
            for (int n = 0; n < 8; ++n) {
                float4 h = *((const float4*)&Hsf[n0 + n][kk]);
                float4 eh = *((const float4*)&EHs[n0 + n][kk]);
                acc1a[n] += h.x * w1a.x + h.y * w1a.y + h.z * w1a.z + h.w * w1a.w;
                acc1b[n] += h.x * w1b.x + h.y * w1b.y + h.z * w1b.z + h.w * w1b.w;
                acc2a[n] += eh.x * w2a.x + eh.y * w2a.y + eh.z * w2a.z + eh.w * w2a.w;
                acc2b[n] += eh.x * w2b.x + eh.y * w2b.y + eh.z * w2b.z + eh.w * w2b.w;
            }
        }
    }
    const float b1a = b1[jg], b1b = b1[jg + 64];
    const float b2a = b2[jg], b2b = b2[jg + 64];
    for (int n = 0; n < 8; ++n) {
        if (n0 + n < nvalid) {
            const int v = v0 + n0 + n;
            float x1 = acc1a[n] + b1a; x1 = x1 > 0.f ? x1 : SLOPE * x1;
            float x2 = acc2a[n] + b2a; x2 = x2 > 0.f ? x2 : SLOPE * x2;
            out[(size_t)v * DD + jg] = x1 + x2;
            float y1 = acc1b[n] + b1b; y1 = y1 > 0.f ? y1 : SLOPE * y1;
            float y2 = acc2b[n] + b2b; y2 = y2 > 0.f ? y2 : SLOPE * y2;
            out[(size_t)v * DD + jg + 64] = y1 + y2;
        }
    }
}
// ===========================================================================

extern "C" void kernel_launch(void* const* d_in, const int* in_sizes, int n_in,
                              void* d_out, int out_size, void* d_ws, size_t ws_size,
                              hipStream_t stream)
{
    const float* E  = (const float*)d_in[0];
    const float* W1 = (const float*)d_in[1];
    const float* b1 = (const float*)d_in[2];
    const float* W2 = (const float*)d_in[3];
    const float* b2 = (const float*)d_in[4];
    const int* src  = (const int*)d_in[5];
    const int* dst  = (const int*)d_in[6];
    float* out = (float*)d_out;
    const int n_edges = in_sizes[5];

    char* ws = (char*)d_ws;
    auto al = [](size_t x) { return (x + 255) & ~(size_t)255; };

    const size_t off_tail = 0;
    const size_t off_ovfc = (size_t)NB * 4;
    const size_t off_ovf  = al(off_ovfc + 4);
    const size_t off_stag = al(off_ovf + (size_t)OVCAP * 8);
    const size_t off_Ebf  = al(off_stag + (size_t)NB * BCAP * 4);
    const size_t off_W1b  = al(off_Ebf + (size_t)NN * DD * 2);
    const size_t off_W2b  = al(off_W1b + (size_t)DD * DD * 2);
    const size_t need_bf  = off_W2b + (size_t)DD * DD * 2;      // ~21 MB

    if (ws_size >= need_bf) {
        int*  gtail   = (int*)(ws + off_tail);
        int*  ovf_cnt = (int*)(ws + off_ovfc);
        int2* ovf     = (int2*)(ws + off_ovf);
        unsigned int*   stag = (unsigned int*)(ws + off_stag);
        unsigned short* Ebf  = (unsigned short*)(ws + off_Ebf);
        unsigned short* W1b  = (unsigned short*)(ws + off_W1b);
        unsigned short* W2b  = (unsigned short*)(ws + off_W2b);

        const int nbin = (n_edges + FECH - 1) / FECH;
        const int ncv  = NN * DD / 8 + 2 * (DD * DD / 8);
        const int ncvb = (ncv + BST - 1) / BST;

        hipMemsetAsync(ws, 0, off_ovf, stream);   // gtail + ovf_cnt
        convert_bin<<<nbin + ncvb, BST, 0, stream>>>(
            E, W1, W2, src, dst, Ebf, W1b, W2b,
            gtail, stag, ovf_cnt, ovf, n_edges, nbin);
        bucket_fused<<<NB, 256, 0, stream>>>(
            Ebf, gtail, stag, ovf_cnt, ovf, W1b, W2b, b1, b2, out);
        return;
    }

    // fallback: fp32 atomics into H (= ws if it fits, else out), then fused MLP
    const size_t hbytes = (size_t)NN * DD * sizeof(float);
    float* H = (ws_size >= hbytes) ? (float*)ws : out;
    hipMemsetAsync(H, 0, hbytes, stream);
    scatter_add<<<((n_edges * 32) + 255) / 256, 256, 0, stream>>>(
        E, src, dst, H, n_edges);
    fused_mlp<<<(NN + 31) / 32, 256, 0, stream>>>(E, H, W1, b1, W2, b2, out);
}

// Round 11
// 195.987 us; speedup vs baseline: 1.8348x; 1.0605x over previous
//
#include <hip/hip_runtime.h>

#define NN 50000
#define DD 128
#define SLOPE 0.01f
#define NB 782        // buckets of 64 nodes: bucket = v>>6
#define BCAP 2560     // per-bucket cap; mean 2046, sigma 45 -> +11 sigma
#define ECH 6144      // edges per bin block
#define BST 512       // convert_bin block threads
#define PB 2          // buckets per thread in prefix scan (512*2 >= 782)
#define OVCAP 8192
#define HP 136        // Hs row pitch (bf16): 272B rows -> even b128 bank groups

using bf16x8 = __attribute__((ext_vector_type(8))) short;
using f32x4  = __attribute__((ext_vector_type(4))) float;

// ---------------- bf16 helpers (RNE) ----------------
__device__ inline float bflo(unsigned int w) { return __uint_as_float(w << 16); }
__device__ inline float bfhi(unsigned int w) { return __uint_as_float(w & 0xffff0000u); }
__device__ inline float sbf(short s) {
    return __uint_as_float(((unsigned int)(unsigned short)s) << 16);
}
__device__ inline unsigned int rnebf(float f) {
    unsigned int u = __float_as_uint(f);
    return (u + 0x7fffu + ((u >> 16) & 1u)) >> 16;
}
__device__ inline unsigned int pack2(float lo, float hi) {
    return rnebf(lo) | (rnebf(hi) << 16);
}
__device__ inline uint4 pack8f(const float* f) {
    uint4 o;
    o.x = pack2(f[0], f[1]); o.y = pack2(f[2], f[3]);
    o.z = pack2(f[4], f[5]); o.w = pack2(f[6], f[7]);
    return o;
}
__device__ inline void addrow(float* acc, uint4 r) {
    acc[0] += bflo(r.x); acc[1] += bfhi(r.x);
    acc[2] += bflo(r.y); acc[3] += bfhi(r.y);
    acc[4] += bflo(r.z); acc[5] += bfhi(r.z);
    acc[6] += bflo(r.w); acc[7] += bfhi(r.w);
}

// ---------------------------------------------------------------------------
// Fused: blocks [0,nbin) do LDS counting-sort binning of ECH edges each;
// blocks [nbin,..) convert E/W1/W2 fp32->bf16. Independent work co-scheduled.
// ---------------------------------------------------------------------------
__global__ __launch_bounds__(BST) void convert_bin(
    const float* __restrict__ E, const float* __restrict__ W1,
    const float* __restrict__ W2, const int* __restrict__ src,
    const int* __restrict__ dst, unsigned short* __restrict__ Ebf,
    unsigned short* __restrict__ W1b, unsigned short* __restrict__ W2b,
    int* __restrict__ gtail, unsigned int* __restrict__ stag,
    int* __restrict__ ovf_cnt, int2* __restrict__ ovf,
    int n_edges, int nbin)
{
    const int tid = threadIdx.x;

    if (blockIdx.x >= nbin) {
        // ---------------- convert branch ----------------
        const int NE8 = NN * DD / 8;      // 800000
        const int NW8 = DD * DD / 8;      // 2048
        int t = (blockIdx.x - nbin) * BST + tid;
        const float* s; unsigned short* d; int idx;
        if (t < NE8)                { s = E;  d = Ebf; idx = t; }
        else if (t < NE8 + NW8)     { s = W1; d = W1b; idx = t - NE8; }
        else if (t < NE8 + 2 * NW8) { s = W2; d = W2b; idx = t - NE8 - NW8; }
        else return;
        float4 a = ((const float4*)s)[(size_t)idx * 2];
        float4 b = ((const float4*)s)[(size_t)idx * 2 + 1];
        uint4 o;
        o.x = pack2(a.x, a.y); o.y = pack2(a.z, a.w);
        o.z = pack2(b.x, b.y); o.w = pack2(b.z, b.w);
        ((uint4*)d)[idx] = o;
        return;
    }

    // ---------------- bin branch: LDS counting sort by bucket ----------------
    __shared__ unsigned int srt[ECH];     // 24 KB
    __shared__ int cnt[NB], off[NB], pos[NB];
    __shared__ int wsum[BST / 64];

    const int e0 = blockIdx.x * ECH;
    const int m = min(ECH, n_edges - e0);

    for (int b = tid; b < NB; b += BST) cnt[b] = 0;
    __syncthreads();

    for (int i = tid; i < m; i += BST)
        atomicAdd(&cnt[dst[e0 + i] >> 6], 1);
    __syncthreads();

    const int lane = tid & 63, w = tid >> 6;
    int b0 = tid * PB;
    int loc[PB]; int s = 0;
    #pragma unroll
    for (int j = 0; j < PB; ++j) {
        int bb = b0 + j;
        int cv = (bb < NB) ? cnt[bb] : 0;
        loc[j] = s; s += cv;
    }
    int incl = s;
    #pragma unroll
    for (int d = 1; d < 64; d <<= 1) {
        int t2 = __shfl_up(incl, d);
        if (lane >= d) incl += t2;
    }
    if (lane == 63) wsum[w] = incl;
    __syncthreads();
    int wbase = 0;
    for (int w2 = 0; w2 < w; ++w2) wbase += wsum[w2];
    int base = wbase + incl - s;
    #pragma unroll
    for (int j = 0; j < PB; ++j) {
        int bb = b0 + j;
        if (bb < NB) { off[bb] = base + loc[j]; pos[bb] = base + loc[j]; }
    }
    __syncthreads();

    for (int i = tid; i < m; i += BST) {
        int v = dst[e0 + i];
        int u = src[e0 + i];
        int p = atomicAdd(&pos[v >> 6], 1);
        srt[p] = (unsigned int)u | ((unsigned int)(v & 63) << 16);
    }
    __syncthreads();

    // flush: one global atomic per nonempty bucket, contiguous run copy
    for (int bb = tid; bb < NB; bb += BST) {
        int c = cnt[bb];
        if (!c) continue;
        int g = atomicAdd(&gtail[bb], c);
        int s0 = off[bb];
        unsigned int* dstp = stag + (size_t)bb * BCAP;
        for (int k = 0; k < c; ++k) {
            int gp = g + k;
            unsigned int r = srt[s0 + k];
            if (gp < BCAP) {
                dstp[gp] = r;
            } else {
                int oi = atomicAdd(ovf_cnt, 1);
                if (oi < OVCAP)
                    ovf[oi] = make_int2((int)(r & 0xffffu),
                                        bb * 64 + (int)((r >> 16) & 63));
            }
        }
    }
}

// ---------------------------------------------------------------------------
// Fused gather + GEMM. One block per bucket (64 nodes):
//   A) counting-sort the bucket's records by node-low6 in LDS
//   B) gather-sum E rows per node (8-deep load pipeline), fold any overflow
//      edges, store H rows as bf16 in LDS (pitch HP)
//   C) 4 waves: wave w does the 16x16x32-MFMA GEMM for rows w*16..w*16+15,
//      EH A-frags rebuilt in-register from Hs * Ebf[v]; fused leaky epilogue.
// ---------------------------------------------------------------------------
__global__ __launch_bounds__(256) void bucket_fused(
    const unsigned short* __restrict__ Ebf, const int* __restrict__ gtail,
    const unsigned int* __restrict__ stag, const int* __restrict__ ovf_cnt,
    const int2* __restrict__ ovf,
    const unsigned short* __restrict__ W1b, const unsigned short* __restrict__ W2b,
    const float* __restrict__ b1, const float* __restrict__ b2,
    float* __restrict__ out)
{
    __shared__ unsigned short sorted[BCAP];       // 5 KB
    __shared__ unsigned short Hs[64][HP];         // 17 KB
    __shared__ int cnt[64], off[65], pos[64];
    __shared__ int s_novf;

    const int b = blockIdx.x;
    const int tid = threadIdx.x;
    int len = gtail[b]; len = len < BCAP ? len : BCAP;
    const unsigned int* seg = stag + (size_t)b * BCAP;

    if (tid == 0) { int t = *ovf_cnt; s_novf = t < OVCAP ? t : OVCAP; }
    if (tid < 64) cnt[tid] = 0;
    __syncthreads();
    for (int i = tid; i < len; i += 256)
        atomicAdd(&cnt[(seg[i] >> 16) & 63], 1);
    __syncthreads();
    if (tid == 0) {
        int a = 0;
        for (int j = 0; j < 64; ++j) { off[j] = a; pos[j] = a; a += cnt[j]; }
        off[64] = a;
    }
    __syncthreads();
    for (int i = tid; i < len; i += 256) {
        unsigned int r = seg[i];
        int p = atomicAdd(&pos[(r >> 16) & 63], 1);
        sorted[p] = (unsigned short)(r & 0xffffu);
    }
    __syncthreads();
    const int novf = s_novf;

    // ---- gather: 16 lanes per node x 16 nodes per pass, 4 passes ----
    const int g = tid >> 4;
    const int c = tid & 15;
    const uint4* E4 = (const uint4*)Ebf;
    for (int p4 = 0; p4 < 4; ++p4) {
        int nl = p4 * 16 + g;
        int v = b * 64 + nl;
        if (v >= NN) continue;
        float acc[8] = {};
        int i = off[nl], e1 = off[nl + 1];
        for (; i + 8 <= e1; i += 8) {
            uint4 r0 = E4[(size_t)sorted[i]     * 16 + c];
            uint4 r1 = E4[(size_t)sorted[i + 1] * 16 + c];
            uint4 r2 = E4[(size_t)sorted[i + 2] * 16 + c];
            uint4 r3 = E4[(size_t)sorted[i + 3] * 16 + c];
            uint4 r4 = E4[(size_t)sorted[i + 4] * 16 + c];
            uint4 r5 = E4[(size_t)sorted[i + 5] * 16 + c];
            uint4 r6 = E4[(size_t)sorted[i + 6] * 16 + c];
            uint4 r7 = E4[(size_t)sorted[i + 7] * 16 + c];
            addrow(acc, r0); addrow(acc, r1); addrow(acc, r2); addrow(acc, r3);
            addrow(acc, r4); addrow(acc, r5); addrow(acc, r6); addrow(acc, r7);
        }
        for (; i + 2 <= e1; i += 2) {
            uint4 r0 = E4[(size_t)sorted[i]     * 16 + c];
            uint4 r1 = E4[(size_t)sorted[i + 1] * 16 + c];
            addrow(acc, r0); addrow(acc, r1);
        }
        if (i < e1) addrow(acc, E4[(size_t)sorted[i] * 16 + c]);

        if (novf > 0) {                    // rare path: fold overflow edges
            for (int k = 0; k < novf; ++k) {
                int2 e = ovf[k];
                if (e.y == v) addrow(acc, E4[(size_t)e.x * 16 + c]);
            }
        }
        *(uint4*)&Hs[nl][c * 8] = pack8f(acc);
    }
    __syncthreads();

    // ---- GEMM: wave w -> node rows w*16 .. w*16+15 ----
    const int wave = tid >> 6;
    const int lane = tid & 63;
    const int v0 = b * 64 + wave * 16;
    if (v0 >= NN) return;                 // only trailing waves of last bucket
    const int m = lane & 15;
    const int quad = lane >> 4;

    bf16x8 aH[4], aE[4];
    const unsigned short* hrow = &Hs[wave * 16 + m][quad * 8];
    const unsigned short* erow = Ebf + (size_t)(v0 + m) * DD + quad * 8;
    #pragma unroll
    for (int ks = 0; ks < 4; ++ks) {
        bf16x8 h8 = *(const bf16x8*)(hrow + ks * 32);
        bf16x8 e8 = *(const bf16x8*)(erow + ks * 32);
        aH[ks] = h8;
        bf16x8 eh;
        #pragma unroll
        for (int j = 0; j < 8; ++j)
            eh[j] = (short)rnebf(sbf(h8[j]) * sbf(e8[j]));
        aE[ks] = eh;
    }

    #pragma unroll
    for (int jt = 0; jt < 8; ++jt) {
        const int j0 = jt * 16;
        const unsigned short* w1r = W1b + (size_t)(j0 + m) * DD + quad * 8;
        const unsigned short* w2r = W2b + (size_t)(j0 + m) * DD + quad * 8;
        f32x4 acc1 = {0.f, 0.f, 0.f, 0.f}, acc2 = {0.f, 0.f, 0.f, 0.f};
        #pragma unroll
        for (int ks = 0; ks < 4; ++ks) {
            bf16x8 bw1 = *(const bf16x8*)(w1r + ks * 32);
            bf16x8 bw2 = *(const bf16x8*)(w2r + ks * 32);
            acc1 = __builtin_amdgcn_mfma_f32_16x16x32_bf16(aH[ks], bw1, acc1, 0, 0, 0);
            acc2 = __builtin_amdgcn_mfma_f32_16x16x32_bf16(aE[ks], bw2, acc2, 0, 0, 0);
        }
        const float bb1 = b1[j0 + m], bb2 = b2[j0 + m];
        #pragma unroll
        for (int i = 0; i < 4; ++i) {
            int row = v0 + quad * 4 + i;
            if (row < NN) {
                float x1 = acc1[i] + bb1; x1 = x1 > 0.f ? x1 : SLOPE * x1;
                float x2 = acc2[i] + bb2; x2 = x2 > 0.f ? x2 : SLOPE * x2;
                out[(size_t)row * DD + j0 + m] = x1 + x2;
            }
        }
    }
}

// ============== minimal fallback (ws too small): fp32 atomics ==============
__global__ __launch_bounds__(256) void scatter_add(
    const float* __restrict__ E, const int* __restrict__ src,
    const int* __restrict__ dst, float* __restrict__ H, int n_edges)
{
    int t = blockIdx.x * 256 + threadIdx.x;
    int e = t >> 5;
    if (e >= n_edges) return;
    int c = t & 31;
    float4 a = ((const float4*)E)[(size_t)src[e] * 32 + c];
    float* hp = H + (size_t)dst[e] * DD + c * 4;
    atomicAdd(hp + 0, a.x); atomicAdd(hp + 1, a.y);
    atomicAdd(hp + 2, a.z); atomicAdd(hp + 3, a.w);
}

__global__ __launch_bounds__(256) void fused_mlp(
    const float* __restrict__ E, const float* __restrict__ H,
    const float* __restrict__ W1, const float* __restrict__ b1,
    const float* __restrict__ W2, const float* __restrict__ b2,
    float* __restrict__ out)
{
    __shared__ float Hsf[32][DD];
    __shared__ float EHs[32][DD];
    __shared__ float W1s[DD][20];
    __shared__ float W2s[DD][20];
    const int tid = threadIdx.x;
    const int v0 = blockIdx.x * 32;
    const int nvalid = min(32, NN - v0);
    for (int i = 0; i < 4; ++i) {
        int f = tid + 256 * i;
        int n = f >> 5, c = f & 31;
        float4 h = make_float4(0.f, 0.f, 0.f, 0.f);
        float4 eh = h;
        if (n < nvalid) {
            h = ((const float4*)H)[(size_t)(v0 + n) * 32 + c];
            float4 e4 = ((const float4*)E)[(size_t)(v0 + n) * 32 + c];
            eh = make_float4(e4.x * h.x, e4.y * h.y, e4.z * h.z, e4.w * h.w);
        }
        *((float4*)&Hsf[n][c * 4]) = h;
        *((float4*)&EHs[n][c * 4]) = eh;
    }
    const int jg = tid & 63;
    const int n0 = (tid >> 6) * 8;
    float acc1a[8] = {}, acc1b[8] = {}, acc2a[8] = {}, acc2b[8] = {};
    for (int t8 = 0; t8 < 8; ++t8) {
        const int k0 = t8 * 16;
        __syncthreads();
        for (int i = 0; i < 8; ++i) {
            int f = tid + 256 * i;
            int j = f >> 4, kk = f & 15;
            W1s[j][kk] = W1[j * DD + k0 + kk];
            W2s[j][kk] = W2[j * DD + k0 + kk];
        }
        __syncthreads();
        for (int c = 0; c < 4; ++c) {
            float4 w1a = *((const float4*)&W1s[jg][c * 4]);
            float4 w1b = *((const float4*)&W1s[jg + 64][c * 4]);
            float4 w2a = *((const float4*)&W2s[jg][c * 4]);
            float4 w2b = *((const float4*)&W2s[jg + 64][c * 4]);
            const int kk = k0 + c * 4;
            for (int n = 0; n < 8; ++n) {
                float4 h = *((const float4*)&Hsf[n0 + n][kk]);
                float4 eh = *((const float4*)&EHs[n0 + n][kk]);
                acc1a[n] += h.x * w1a.x + h.y * w1a.y + h.z * w1a.z + h.w * w1a.w;
                acc1b[n] += h.x * w1b.x + h.y * w1b.y + h.z * w1b.z + h.w * w1b.w;
                acc2a[n] += eh.x * w2a.x + eh.y * w2a.y + eh.z * w2a.z + eh.w * w2a.w;
                acc2b[n] += eh.x * w2b.x + eh.y * w2b.y + eh.z * w2b.z + eh.w * w2b.w;
            }
        }
    }
    const float b1a = b1[jg], b1b = b1[jg + 64];
    const float b2a = b2[jg], b2b = b2[jg + 64];
    for (int n = 0; n < 8; ++n) {
        if (n0 + n < nvalid) {
            const int v = v0 + n0 + n;
            float x1 = acc1a[n] + b1a; x1 = x1 > 0.f ? x1 : SLOPE * x1;
            float x2 = acc2a[n] + b2a; x2 = x2 > 0.f ? x2 : SLOPE * x2;
            out[(size_t)v * DD + jg] = x1 + x2;
            float y1 = acc1b[n] + b1b; y1 = y1 > 0.f ? y1 : SLOPE * y1;
            float y2 = acc2b[n] + b2b; y2 = y2 > 0.f ? y2 : SLOPE * y2;
            out[(size_t)v * DD + jg + 64] = y1 + y2;
        }
    }
}
// ===========================================================================

extern "C" void kernel_launch(void* const* d_in, const int* in_sizes, int n_in,
                              void* d_out, int out_size, void* d_ws, size_t ws_size,
                              hipStream_t stream)
{
    const float* E  = (const float*)d_in[0];
    const float* W1 = (const float*)d_in[1];
    const float* b1 = (const float*)d_in[2];
    const float* W2 = (const float*)d_in[3];
    const float* b2 = (const float*)d_in[4];
    const int* src  = (const int*)d_in[5];
    const int* dst  = (const int*)d_in[6];
    float* out = (float*)d_out;
    const int n_edges = in_sizes[5];

    char* ws = (char*)d_ws;
    auto al = [](size_t x) { return (x + 255) & ~(size_t)255; };

    const size_t off_tail = 0;                                  // NB*4
    const size_t off_ovfc = (size_t)NB * 4;
    const size_t off_ovf  = al(off_ovfc + 4);
    const size_t off_stag = al(off_ovf + (size_t)OVCAP * 8);
    const size_t off_Ebf  = al(off_stag + (size_t)NB * BCAP * 4);
    const size_t off_W1b  = al(off_Ebf + (size_t)NN * DD * 2);
    const size_t off_W2b  = al(off_W1b + (size_t)DD * DD * 2);
    const size_t need_bf  = off_W2b + (size_t)DD * DD * 2;      // ~21 MB

    if (ws_size >= need_bf) {
        int*  gtail   = (int*)(ws + off_tail);
        int*  ovf_cnt = (int*)(ws + off_ovfc);
        int2* ovf     = (int2*)(ws + off_ovf);
        unsigned int*   stag = (unsigned int*)(ws + off_stag);
        unsigned short* Ebf  = (unsigned short*)(ws + off_Ebf);
        unsigned short* W1b  = (unsigned short*)(ws + off_W1b);
        unsigned short* W2b  = (unsigned short*)(ws + off_W2b);

        const int nbin = (n_edges + ECH - 1) / ECH;
        const int ncv  = NN * DD / 8 + 2 * (DD * DD / 8);
        const int ncvb = (ncv + BST - 1) / BST;

        hipMemsetAsync(ws, 0, off_ovf, stream);   // gtail + ovf_cnt
        convert_bin<<<nbin + ncvb, BST, 0, stream>>>(
            E, W1, W2, src, dst, Ebf, W1b, W2b,
            gtail, stag, ovf_cnt, ovf, n_edges, nbin);
        bucket_fused<<<NB, 256, 0, stream>>>(
            Ebf, gtail, stag, ovf_cnt, ovf, W1b, W2b, b1, b2, out);
        return;
    }

    // fallback: fp32 atomics into H (= ws if it fits, else out), then fused MLP
    const size_t hbytes = (size_t)NN * DD * sizeof(float);
    float* H = (ws_size >= hbytes) ? (float*)ws : out;
    hipMemsetAsync(H, 0, hbytes, stream);
    scatter_add<<<((n_edges * 32) + 255) / 256, 256, 0, stream>>>(
        E, src, dst, H, n_edges);
    fused_mlp<<<(NN + 31) / 32, 256, 0, stream>>>(E, H, W1, b1, W2, b2, out);
}